// Round 3
// baseline (531.344 us; speedup 1.0000x reference)
//
#include <hip/hip_runtime.h>

// Flip to 0 if absmax fails large: selects legacy (non-partitionable) JAX threefry stream.
#define JAX_THREEFRY_PARTITIONABLE 1

namespace {

constexpr int BN   = 2;      // batch
constexpr int C0   = 64;
constexpr int HH   = 100;
constexpr int WWW  = 100;
constexpr int LL   = 10000;  // H*W
constexpr int TL   = 20000;  // 2L
constexpr int CHK  = 144;
constexpr int NCHK = 139;    // (TL+16)/144
constexpr int NPAD = 16;
constexpr int WINR = 432;    // 3*144

// ws layout in float slots
constexpr int OFF_ROT  = 0;                    // rotT [4][64][16]
constexpr int OFF_WT1  = OFF_ROT + 4096;       // [64*9][16]
constexpr int OFF_WT2  = OFF_WT1 + 9216;       // [16*9][16]
constexpr int OFF_WTS  = OFF_WT2 + 2304;       // [64][16]
constexpr int OFF_HT0  = OFF_WTS + 1024;       // conv1 partial kh=0 [4][16][10000]
constexpr int OFF_HT1  = OFF_HT0 + 640000;     // conv1 partial kh=1
constexpr int OFF_F    = OFF_HT1 + 640000;     // F [2][20000][16]
constexpr int OFF_SC   = OFF_F + 640000;       // SC [2][136]
constexpr int OFF_AB   = OFF_SC + 272;         // AB [2][20000][2]
constexpr int OFF_CODE = OFF_AB + 80000;       // codes u8 [8][20000]
constexpr int OFF_RANK = OFF_CODE + 40000;     // rank int [8][20000]
constexpr int OFF_N0   = OFF_RANK + 160000;    // n0 int [8][139]
constexpr int OFF_INV  = OFF_N0 + 1112;        // inv int [10000]
constexpr int OFF_AUX  = OFF_INV + 10000;      // auxT: 4 x [576][64]

constexpr int AUXW = 36864;  // 64*64*9

__device__ __forceinline__ unsigned rotl32(unsigned v, int r) {
  return (v << r) | (v >> (32 - r));
}

// JAX threefry2x32, 20 rounds, key injection every 4.
__device__ void tf2x32(unsigned k0, unsigned k1, unsigned x0, unsigned x1,
                       unsigned& o0, unsigned& o1) {
  unsigned ks2 = k0 ^ k1 ^ 0x1BD11BDAu;
  x0 += k0; x1 += k1;
#define TFR(r) { x0 += x1; x1 = rotl32(x1, r); x1 ^= x0; }
  TFR(13) TFR(15) TFR(26) TFR(6)  x0 += k1;  x1 += ks2 + 1u;
  TFR(17) TFR(29) TFR(16) TFR(24) x0 += ks2; x1 += k0 + 2u;
  TFR(13) TFR(15) TFR(26) TFR(6)  x0 += k0;  x1 += k1 + 3u;
  TFR(17) TFR(29) TFR(16) TFR(24) x0 += k1;  x1 += ks2 + 4u;
  TFR(13) TFR(15) TFR(26) TFR(6)  x0 += ks2; x1 += k0 + 5u;
#undef TFR
  o0 = x0; o1 = x1;
}

// XLA's ErfInv32 polynomial (math.cc), no fp contraction to match XLA rounding.
__device__ float xla_erfinv(float x) {
#pragma clang fp contract(off)
  float w = -log1pf(-x * x);
  float p;
  if (w < 5.0f) {
    w = w - 2.5f;
    p = 2.81022636e-08f;
    p = 3.43273939e-07f  + p * w;
    p = -3.5233877e-06f  + p * w;
    p = -4.39150654e-06f + p * w;
    p = 0.00021858087f   + p * w;
    p = -0.00125372503f  + p * w;
    p = -0.00417768164f  + p * w;
    p = 0.246640727f     + p * w;
    p = 1.50140941f      + p * w;
  } else {
    w = sqrtf(w) - 3.0f;
    p = -0.000200214257f;
    p = 0.000100950558f + p * w;
    p = 0.00134934322f  + p * w;
    p = -0.00367342844f + p * w;
    p = 0.00573950773f  + p * w;
    p = -0.0076224613f  + p * w;
    p = 0.00943887047f  + p * w;
    p = 1.00167406f     + p * w;
    p = 2.83297682f     + p * w;
  }
  return p * x;
}

// Merged prep: aux weight transposes + rot RNG + m-weight transposes + inv perm.
__global__ void k_prep(const float* __restrict__ mw1, const float* __restrict__ mw2,
                       const float* __restrict__ mws,
                       const float* __restrict__ a1w1, const float* __restrict__ a1w2,
                       const float* __restrict__ a2w1, const float* __restrict__ a2w2,
                       const int* __restrict__ ri,
                       float* __restrict__ rotT, float* __restrict__ wT1,
                       float* __restrict__ wT2, float* __restrict__ wTs,
                       float* __restrict__ auxT, int* __restrict__ inv) {
  int gid = blockIdx.x * 256 + threadIdx.x;
  if (gid < 4 * AUXW) {
    int wsel = gid / AUXW, j = gid % AUXW;
    const float* src = (wsel == 0) ? a1w1 : (wsel == 1) ? a1w2 : (wsel == 2) ? a2w1 : a2w2;
    int co = j / 576, r = j % 576;                 // coalesced read
    auxT[wsel * AUXW + r * 64 + co] = src[j];
    return;
  }
  int g2 = gid - 4 * AUXW;
  if (g2 < 4096) {
    int i = g2;
    unsigned o0, o1, bits;
#if JAX_THREEFRY_PARTITIONABLE
    tf2x32(0u, 42u, 0u, (unsigned)i, o0, o1);
    bits = o0 ^ o1;
#else
    if (i < 2048) { tf2x32(0u, 42u, (unsigned)i, (unsigned)(i + 2048), o0, o1); bits = o0; }
    else          { tf2x32(0u, 42u, (unsigned)(i - 2048), (unsigned)i, o0, o1); bits = o1; }
#endif
    unsigned fb = (bits >> 9) | 0x3f800000u;
    float f = __uint_as_float(fb) - 1.0f;
    const float lo = __uint_as_float(0xBF7FFFFFu);  // nextafter(-1,0)
    float u = fmaxf(lo, f * 2.0f + lo);
    float r = __uint_as_float(0x3FB504F3u) * xla_erfinv(u);  // sqrt(2)*erfinv(u)
    int c = i >> 8, h = (i >> 6) & 3, j = i & 63;
    rotT[(h * 64 + j) * 16 + c] = r;
    return;
  }
  int g3 = g2 - 4096;
  if (g3 < 9216) {
    { int o = g3 / 576; int r = g3 % 576; wT1[r * 16 + o] = mw1[g3]; }
    if (g3 < 2304) { int o = g3 / 144; int r = g3 % 144; wT2[r * 16 + o] = mw2[g3]; }
    if (g3 < 1024) { int o = g3 / 64;  int ci = g3 % 64; wTs[ci * 16 + o] = mws[g3]; }
    return;
  }
  int g4 = g3 - 9216;
  if (g4 < TL) {
    int p = ri[g4];
    if (p < LL) inv[p] = g4;
  }
}

// conv1 (m-block, 64->16 3x3), K-split in 2 halves of 32 ci.
// block = (img n, khalf, 16x16 tile); thread = (co, y-row) over 16-px x-strip.
// Weights register-stationary per 8-ci chunk; partial sums (no bias/relu) to ht0/ht1.
__global__ __launch_bounds__(256) void k_conv1(
    const float* __restrict__ fd1, const float* __restrict__ fd2,
    const float* __restrict__ wT1,
    float* __restrict__ ht0, float* __restrict__ ht1) {
  int blk = blockIdx.x;
  int kh = blk & 1;
  int rest = blk >> 1;
  int n = rest / 49, tile = rest % 49;
  int ty0 = (tile / 7) * 16, tx0 = (tile % 7) * 16;
  const float* in = ((n >> 1) ? fd2 : fd1) + (n & 1) * (C0 * LL) + (kh * 32) * LL;
  float* htk = (kh ? ht1 : ht0) + n * 16 * LL;
  int tid = threadIdx.x;
  int co = tid & 15, yl = tid >> 4;

  __shared__ float sIn[32 * 18 * 20];   // [ci][18 rows][20 pad] halo tile
  __shared__ float sW[288 * 16];        // this half's weights [(ci*9+t)][co]

  // stage weights (contiguous)
  for (int i = tid; i < 288 * 16; i += 256) sW[i] = wT1[kh * 4608 + i];
  // stage input halo tile, zero-padded
  for (int idx = tid; idx < 32 * 18 * 18; idx += 256) {
    int ci = idx / 324, r = idx % 324, iy = r / 18, ix = r % 18;
    int gy = ty0 - 1 + iy, gx = tx0 - 1 + ix;
    float v = 0.f;
    if (gy >= 0 && gy < HH && gx >= 0 && gx < WWW) v = in[ci * LL + gy * WWW + gx];
    sIn[ci * 360 + iy * 20 + ix] = v;
  }
  __syncthreads();

  float acc[16];
#pragma unroll
  for (int p = 0; p < 16; ++p) acc[p] = 0.f;

  for (int cc = 0; cc < 4; ++cc) {   // 8-ci chunks
    float w[8][9];
#pragma unroll
    for (int c8 = 0; c8 < 8; ++c8)
#pragma unroll
      for (int t = 0; t < 9; ++t)
        w[c8][t] = sW[((cc * 8 + c8) * 9 + t) * 16 + co];
#pragma unroll
    for (int c8 = 0; c8 < 8; ++c8) {
      const float* rowb = &sIn[(cc * 8 + c8) * 360 + yl * 20];
#pragma unroll
      for (int dy = 0; dy < 3; ++dy) {
        const float* r = rowb + dy * 20;
        float v[18];
#pragma unroll
        for (int k = 0; k < 18; ++k) v[k] = r[k];
#pragma unroll
        for (int dx = 0; dx < 3; ++dx) {
          float wv = w[c8][dy * 3 + dx];
#pragma unroll
          for (int p = 0; p < 16; ++p) acc[p] = fmaf(v[p + dx], wv, acc[p]);
        }
      }
    }
  }

  int yv = ty0 + yl;
  if (yv < HH) {
    float* op = htk + co * LL + yv * WWW;
#pragma unroll
    for (int g = 0; g < 4; ++g) {
      int xg = tx0 + g * 4;
      if (xg < WWW) {
        float4 s = make_float4(acc[g * 4], acc[g * 4 + 1], acc[g * 4 + 2], acc[g * 4 + 3]);
        *(float4*)&op[xg] = s;
      }
    }
  }
}

// conv2 (16->16 3x3 + b2) + skip (1x1 64->16 + mbs) on h = relu(ht0+ht1+mb1).
// block = (img n, 16y x 8x tile); thread = (co, y) over 8-px strip.
__global__ __launch_bounds__(256) void k_conv2(
    const float* __restrict__ fd1, const float* __restrict__ fd2,
    const float* __restrict__ ht0, const float* __restrict__ ht1,
    const float* __restrict__ wT2, const float* __restrict__ mb1,
    const float* __restrict__ mb2, const float* __restrict__ wTs,
    const float* __restrict__ mbs, float* __restrict__ F) {
  int blk = blockIdx.x;
  int n = blk / 91, tile = blk % 91;
  int yt = tile / 13, xt = tile % 13;
  int ty0 = yt * 16, tx0 = xt * 8;
  int src = n >> 1, b = n & 1;
  const float* in = (src ? fd2 : fd1) + b * (C0 * LL);
  const float* h0 = ht0 + n * 16 * LL;
  const float* h1 = ht1 + n * 16 * LL;
  int tid = threadIdx.x;
  int co = tid & 15, yl = tid >> 4;

  __shared__ float sH[16 * 18 * 12];    // h halo tile [ci][18][12 pad(10 used)]
  __shared__ float sSkip[64 * 16 * 8];  // skip input center [ci][16][8]
  __shared__ float sW2[144 * 16];
  __shared__ float sWs[64 * 16];

  for (int i = tid; i < 144 * 16; i += 256) sW2[i] = wT2[i];
  for (int i = tid; i < 64 * 16; i += 256) sWs[i] = wTs[i];
  for (int idx = tid; idx < 16 * 18 * 10; idx += 256) {
    int ci = idx / 180, r = idx % 180, iy = r / 10, ix = r % 10;
    int gy = ty0 - 1 + iy, gx = tx0 - 1 + ix;
    float v = 0.f;
    if (gy >= 0 && gy < HH && gx >= 0 && gx < WWW) {
      int o = ci * LL + gy * WWW + gx;
      v = fmaxf(h0[o] + h1[o] + mb1[ci], 0.f);
    }
    sH[ci * 216 + iy * 12 + ix] = v;
  }
  for (int idx = tid; idx < 64 * 16 * 8; idx += 256) {
    int ci = idx / 128, r = idx % 128, iy = r / 8, ix = r % 8;
    int gy = ty0 + iy, gx = tx0 + ix;
    float v = 0.f;
    if (gy < HH && gx < WWW) v = in[ci * LL + gy * WWW + gx];
    sSkip[ci * 128 + iy * 8 + ix] = v;
  }
  __syncthreads();

  float bias = mb2[co] + mbs[co];
  float acc[8];
#pragma unroll
  for (int p = 0; p < 8; ++p) acc[p] = bias;

  for (int cc = 0; cc < 2; ++cc) {   // conv 3x3 over 16 h-channels, 8-ci chunks
    float w[8][9];
#pragma unroll
    for (int c8 = 0; c8 < 8; ++c8)
#pragma unroll
      for (int t = 0; t < 9; ++t)
        w[c8][t] = sW2[((cc * 8 + c8) * 9 + t) * 16 + co];
#pragma unroll
    for (int c8 = 0; c8 < 8; ++c8) {
      const float* rowb = &sH[(cc * 8 + c8) * 216 + yl * 12];
#pragma unroll
      for (int dy = 0; dy < 3; ++dy) {
        const float* r = rowb + dy * 12;
        float v[10];
#pragma unroll
        for (int k = 0; k < 10; ++k) v[k] = r[k];
#pragma unroll
        for (int dx = 0; dx < 3; ++dx) {
          float wv = w[c8][dy * 3 + dx];
#pragma unroll
          for (int p = 0; p < 8; ++p) acc[p] = fmaf(v[p + dx], wv, acc[p]);
        }
      }
    }
  }
  for (int cc = 0; cc < 8; ++cc) {   // skip 1x1 over 64 ci, 8-ci chunks
    float w[8];
#pragma unroll
    for (int c8 = 0; c8 < 8; ++c8) w[c8] = sWs[(cc * 8 + c8) * 16 + co];
#pragma unroll
    for (int c8 = 0; c8 < 8; ++c8) {
      const float* sv = &sSkip[(cc * 8 + c8) * 128 + yl * 8];
#pragma unroll
      for (int p = 0; p < 8; ++p) acc[p] = fmaf(sv[p], w[c8], acc[p]);
    }
  }

  int yv = ty0 + yl;
  if (yv < HH) {
    float* Fb = F + (b * TL + src * LL + yv * WWW) * 16 + co;
#pragma unroll
    for (int p = 0; p < 8; ++p) {
      int xv = tx0 + p;
      if (xv < WWW) Fb[xv * 16] = acc[p];
    }
  }
}

// codes in permuted order: code[bh][t'] = argmax over [rv, -rv] at row ri[t']
__global__ __launch_bounds__(256) void k_codes(
    const float* __restrict__ F, const float* __restrict__ rotT,
    const int* __restrict__ ri, unsigned char* __restrict__ codes) {
  int bh = blockIdx.y;
  int b = bh >> 2, h = bh & 3;
  __shared__ float srot[1024];
  int tid = threadIdx.x;
  for (int i = tid; i < 1024; i += 256) srot[i] = rotT[h * 1024 + i];
  __syncthreads();
  int t = blockIdx.x * 256 + tid;
  if (t >= TL) return;
  int pos = ri[t];
  const float* Fr = F + (b * TL + pos) * 16;
  float q[16];
#pragma unroll
  for (int c = 0; c < 16; ++c) q[c] = Fr[c];
  float best = -1e30f; int bi = 0;
  float worst = 1e30f; int wi = 0;
  for (int j = 0; j < 64; ++j) {
    float v = 0.f;
    const float* rp = srot + j * 16;
#pragma unroll
    for (int c = 0; c < 16; ++c) v = fmaf(q[c], rp[c], v);
    if (v > best)  { best = v;  bi = j; }
    if (v < worst) { worst = v; wi = j; }
  }
  int code = (best >= -worst) ? bi : (64 + wi);
  codes[bh * TL + t] = (unsigned char)code;
}

// stable counting sort per (b,h); emit rank_of[t'] and even-parity chunk counts n0
__global__ __launch_bounds__(256) void k_sort(
    const unsigned char* __restrict__ codes,
    int* __restrict__ rank_of, int* __restrict__ n0g) {
  int bh = blockIdx.x;
  const unsigned char* keys = codes + bh * TL;
  __shared__ unsigned short cnt[240][128];
  __shared__ unsigned int totals[128];
  __shared__ unsigned int baseoff[128];
  __shared__ unsigned int n0s[NCHK];
  int tid = threadIdx.x;
  for (int i = tid; i < 240 * 128 / 2; i += 256) ((unsigned int*)cnt)[i] = 0u;
  for (int i = tid; i < NCHK; i += 256) n0s[i] = 0u;
  __syncthreads();
  const int SEG = 84;
  int base = tid * SEG;
  int nloc = (tid < 240) ? (TL - base) : 0;
  if (nloc > SEG) nloc = SEG;
  if (nloc < 0) nloc = 0;
  for (int e = 0; e < nloc; ++e) cnt[tid][keys[base + e]]++;
  __syncthreads();
  if (tid < 128) {
    unsigned int s = 0;
    for (int g = 0; g < 240; ++g) s += cnt[g][tid];
    totals[tid] = s;
  }
  __syncthreads();
  if (tid == 0) {
    unsigned int run = 0;
    for (int c = 0; c < 128; ++c) { baseoff[c] = run; run += totals[c]; }
  }
  __syncthreads();
  if (tid < 128) {
    unsigned int run = baseoff[tid];
    for (int g = 0; g < 240; ++g) {
      unsigned int v = cnt[g][tid];
      cnt[g][tid] = (unsigned short)run;
      run += v;
    }
  }
  __syncthreads();
  for (int e = 0; e < nloc; ++e) {
    int idx = base + e;
    int c = keys[idx];
    int r = cnt[tid][c]++;
    rank_of[bh * TL + idx] = r;
    if (!(idx & 1)) {
      atomicAdd(&n0s[r / CHK], 1u);
      if (r >= TL - NPAD) atomicAdd(&n0s[NCHK - 1], 1u);
    }
  }
  __syncthreads();
  for (int i = tid; i < NCHK; i += 256) n0g[bh * NCHK + i] = (int)n0s[i];
}

// blocks 0..3: rA/rB point-resblock, LDS-staged; block 4: per-batch E scalars.
__global__ __launch_bounds__(576) void k_point(
    const float* __restrict__ fd1, const float* __restrict__ refin,
    const int* __restrict__ ri, const float* __restrict__ auxT,
    const float* __restrict__ a1b1, const float* __restrict__ a1b2,
    const float* __restrict__ a2b1, const float* __restrict__ a2b2,
    const float* __restrict__ F, float* __restrict__ SC) {
  int tid = threadIdx.x;
  if (blockIdx.x == 4) {
#pragma clang fp contract(off)
    int b = tid;
    if (b >= BN) return;
    int j0 = ri[0], jL = ri[LL];
    const float* qA = F + (b * TL + j0) * 16;
    const float* qB = F + (b * TL + jL) * 16;
    float nA = 0.f, nB = 0.f;
    for (int c = 0; c < 16; ++c) { nA += qA[c] * qA[c]; nB += qB[c] * qB[c]; }
    float mA = fmaxf(sqrtf(nA), 5e-5f), mB = fmaxf(sqrtf(nB), 5e-5f);
    float d00 = 0.f, d01 = 0.f, d10 = 0.f, d11 = 0.f;
    for (int c = 0; c < 16; ++c) {
      float kAc = qA[c] / mA, kBc = qB[c] / mB;
      d00 += qA[c] * kAc; d01 += qA[c] * kBc;
      d10 += qB[c] * kAc; d11 += qB[c] * kBc;
    }
    float zA = (j0 < LL) ? 0.01f : 0.99f;
    float zB = (jL < LL) ? 0.01f : 0.99f;
    float* sc = SC + b * 136;
    sc[0] = expf(d00) * zA; sc[1] = expf(d01) * zB;
    sc[2] = expf(d10) * zA; sc[3] = expf(d11) * zB;
    return;
  }
  int b = blockIdx.x & 1, which = blockIdx.x >> 1;
  int pos = ri[which * LL];
  const float *in, *w1T, *b1, *w2T, *b2;
  int sp;
  if (pos < LL) {
    in = fd1 + b * C0 * LL; w1T = auxT; b1 = a1b1; w2T = auxT + AUXW; b2 = a1b2; sp = pos;
  } else {
    in = refin + b * C0 * LL; w1T = auxT + 2 * AUXW; b1 = a2b1; w2T = auxT + 3 * AUXW;
    b2 = a2b2; sp = pos - LL;
  }
  int y = sp / WWW, x = sp % WWW;

  __shared__ float sPatch[64][25];
  __shared__ float sW[144 * 64];
  __shared__ float sH[9][64];
  __shared__ float sPart[9][64];

  for (int idx = tid; idx < 64 * 25; idx += 576) {
    int ci = idx / 25, pp = idx % 25;
    int gy = y - 2 + pp / 5, gx = x - 2 + pp % 5;
    float v = 0.f;
    if (gy >= 0 && gy < HH && gx >= 0 && gx < WWW) v = in[ci * LL + gy * WWW + gx];
    sPatch[ci][pp] = v;
  }

  int p = tid / 64, ch = tid & 63;
  int p3 = p / 3, pm = p % 3;
  int yy = y + p3 - 1, xx = x + pm - 1;
  bool inb = (yy >= 0) && (yy < HH) && (xx >= 0) && (xx < WWW);

  float acc0 = 0.f, acc1 = 0.f;
  for (int cc = 0; cc < 4; ++cc) {
    __syncthreads();
    for (int i = tid; i < 144 * 64; i += 576) sW[i] = w1T[cc * 9216 + i];
    __syncthreads();
    if (inb) {
#pragma unroll
      for (int ci = 0; ci < 16; ++ci) {
        const float* wp = &sW[ci * 9 * 64 + ch];
        const float* pr = &sPatch[cc * 16 + ci][0];
#pragma unroll
        for (int t = 0; t < 9; ++t) {
          float v = pr[(p3 + t / 3) * 5 + (pm + t % 3)];
          if (ci & 1) acc1 = fmaf(v, wp[t * 64], acc1);
          else        acc0 = fmaf(v, wp[t * 64], acc0);
        }
      }
    }
  }
  sH[p][ch] = inb ? fmaxf(acc0 + acc1 + b1[ch], 0.f) : 0.f;
  __syncthreads();

  {
    float part = 0.f;
    const float* wbase = w2T + p * 64 + ch;
    for (int ci = 0; ci < 64; ++ci) part = fmaf(sH[p][ci], wbase[ci * 9 * 64], part);
    sPart[p][ch] = part;
  }
  __syncthreads();
  if (tid < 64) {
    int co = tid;
    float a = in[co * LL + y * WWW + x] + b2[co];
#pragma unroll
    for (int g = 0; g < 9; ++g) a += sPart[g][co];
    SC[b * 136 + 4 + which * 64 + co] = a;
  }
}

// per (b, t'): alpha/beta = hash-summed numerators over hash-summed denominators
__global__ void k_ab(const int* __restrict__ rank_of, const int* __restrict__ n0,
                     const float* __restrict__ SC, float* __restrict__ AB) {
  int gid = blockIdx.x * 256 + threadIdx.x;
  if (gid >= BN * TL) return;
  int b = gid / TL, t = gid % TL;
  int si = t & 1;
  float e0 = SC[b * 136 + si * 2 + 0];
  float e1 = SC[b * 136 + si * 2 + 1];
  float s0 = 0.f, s1 = 0.f;
  for (int h = 0; h < 4; ++h) {
    int r = rank_of[(b * 4 + h) * TL + t];
    int k = r / CHK;
    int km = (k == 0) ? NCHK - 1 : k - 1;
    int kp = (k == NCHK - 1) ? 0 : k + 1;
    const int* nb = n0 + (b * 4 + h) * NCHK;
    int W0 = nb[k] + nb[km] + nb[kp];
    s0 += (float)W0 * e0;
    s1 += (float)(WINR - W0) * e1;
  }
  float invd = 1.f / (s0 + s1);
  AB[(b * TL + t) * 2 + 0] = s0 * invd;
  AB[(b * TL + t) * 2 + 1] = s1 * invd;
}

// out[b][c][p] = alpha*rA[c] + beta*rB[c], p < L
__global__ __launch_bounds__(256) void k_out(
    const int* __restrict__ inv, const float* __restrict__ AB,
    const float* __restrict__ SC, float* __restrict__ out) {
  int b = blockIdx.y;
  int p = blockIdx.x * 256 + threadIdx.x;
  if (p >= LL) return;
  int t = inv[p];
  float al = AB[(b * TL + t) * 2 + 0];
  float be = AB[(b * TL + t) * 2 + 1];
  const float* rA = SC + b * 136 + 4;
  const float* rB = rA + 64;
  float* o = out + b * C0 * LL + p;
#pragma unroll
  for (int c = 0; c < 64; ++c) o[c * LL] = al * rA[c] + be * rB[c];
}

}  // namespace

extern "C" void kernel_launch(void* const* d_in, const int* in_sizes, int n_in,
                              void* d_out, int out_size, void* d_ws, size_t ws_size,
                              hipStream_t stream) {
  const float* fd1  = (const float*)d_in[0];
  const float* fd2  = (const float*)d_in[1];
  const float* reff = (const float*)d_in[2];
  const int*   ri   = (const int*)d_in[3];
  const float* mw1  = (const float*)d_in[4];
  const float* mb1  = (const float*)d_in[5];
  const float* mw2  = (const float*)d_in[6];
  const float* mb2  = (const float*)d_in[7];
  const float* mws  = (const float*)d_in[8];
  const float* mbs  = (const float*)d_in[9];
  const float* a1w1 = (const float*)d_in[10];
  const float* a1b1 = (const float*)d_in[11];
  const float* a1w2 = (const float*)d_in[12];
  const float* a1b2 = (const float*)d_in[13];
  const float* a2w1 = (const float*)d_in[14];
  const float* a2b1 = (const float*)d_in[15];
  const float* a2w2 = (const float*)d_in[16];
  const float* a2b2 = (const float*)d_in[17];

  float* ws = (float*)d_ws;
  float* rotT = ws + OFF_ROT;
  float* wT1  = ws + OFF_WT1;
  float* wT2  = ws + OFF_WT2;
  float* wTs  = ws + OFF_WTS;
  float* ht0  = ws + OFF_HT0;
  float* ht1  = ws + OFF_HT1;
  float* F    = ws + OFF_F;
  float* SC   = ws + OFF_SC;
  float* AB   = ws + OFF_AB;
  unsigned char* codes = (unsigned char*)(ws + OFF_CODE);
  int* rank_of = (int*)(ws + OFF_RANK);
  int* n0      = (int*)(ws + OFF_N0);
  int* invp    = (int*)(ws + OFF_INV);
  float* auxT  = ws + OFF_AUX;

  k_prep<<<dim3(707), dim3(256), 0, stream>>>(mw1, mw2, mws, a1w1, a1w2, a2w1, a2w2,
                                              ri, rotT, wT1, wT2, wTs, auxT, invp);
  k_conv1<<<dim3(392), dim3(256), 0, stream>>>(fd1, fd2, wT1, ht0, ht1);
  k_conv2<<<dim3(364), dim3(256), 0, stream>>>(fd1, fd2, ht0, ht1, wT2, mb1, mb2,
                                               wTs, mbs, F);
  k_codes<<<dim3(79, 8), dim3(256), 0, stream>>>(F, rotT, ri, codes);
  k_sort<<<dim3(8), dim3(256), 0, stream>>>(codes, rank_of, n0);
  k_point<<<dim3(5), dim3(576), 0, stream>>>(fd1, reff, ri, auxT, a1b1, a1b2,
                                             a2b1, a2b2, F, SC);
  k_ab<<<dim3(157), dim3(256), 0, stream>>>(rank_of, n0, SC, AB);
  k_out<<<dim3(40, 2), dim3(256), 0, stream>>>(invp, AB, SC, (float*)d_out);
}

// Round 4
// 182.695 us; speedup vs baseline: 2.9084x; 2.9084x over previous
//
#include <hip/hip_runtime.h>

// Flip to 0 if absmax fails large: selects legacy (non-partitionable) JAX threefry stream.
#define JAX_THREEFRY_PARTITIONABLE 1

namespace {

constexpr int BN   = 2;      // batch
constexpr int C0   = 64;
constexpr int HH   = 100;
constexpr int WWW  = 100;
constexpr int LL   = 10000;  // H*W
constexpr int TL   = 20000;  // 2L
constexpr int CHK  = 144;
constexpr int NCHK = 139;    // (TL+16)/144
constexpr int NPAD = 16;
constexpr int WINR = 432;    // 3*144

// ws layout in float slots
constexpr int OFF_ROT  = 0;                    // rotT [4][64][16]
constexpr int OFF_WT1  = OFF_ROT + 4096;       // [64*9][16]
constexpr int OFF_WT2  = OFF_WT1 + 9216;       // [16*9][16]
constexpr int OFF_WTS  = OFF_WT2 + 2304;       // [64][16]
constexpr int OFF_HT0  = OFF_WTS + 1024;       // conv1 partial kh=0 [4][16][10000]
constexpr int OFF_HT1  = OFF_HT0 + 640000;     // conv1 partial kh=1
constexpr int OFF_F    = OFF_HT1 + 640000;     // F [2][20000][16]
constexpr int OFF_SC   = OFF_F + 640000;       // SC [2][136]
constexpr int OFF_AB   = OFF_SC + 272;         // AB [2][20000][2]
constexpr int OFF_CODE = OFF_AB + 80000;       // codes u8 [8][20000]
constexpr int OFF_RANK = OFF_CODE + 40000;     // rank int [8][20000]
constexpr int OFF_N0   = OFF_RANK + 160000;    // n0 int [8][139]
constexpr int OFF_INV  = OFF_N0 + 1112;        // inv int [10000]
constexpr int OFF_AUX  = OFF_INV + 10000;      // auxT: 4 x [576][64]

constexpr int AUXW = 36864;  // 64*64*9

__device__ __forceinline__ unsigned rotl32(unsigned v, int r) {
  return (v << r) | (v >> (32 - r));
}

// JAX threefry2x32, 20 rounds, key injection every 4.
__device__ void tf2x32(unsigned k0, unsigned k1, unsigned x0, unsigned x1,
                       unsigned& o0, unsigned& o1) {
  unsigned ks2 = k0 ^ k1 ^ 0x1BD11BDAu;
  x0 += k0; x1 += k1;
#define TFR(r) { x0 += x1; x1 = rotl32(x1, r); x1 ^= x0; }
  TFR(13) TFR(15) TFR(26) TFR(6)  x0 += k1;  x1 += ks2 + 1u;
  TFR(17) TFR(29) TFR(16) TFR(24) x0 += ks2; x1 += k0 + 2u;
  TFR(13) TFR(15) TFR(26) TFR(6)  x0 += k0;  x1 += k1 + 3u;
  TFR(17) TFR(29) TFR(16) TFR(24) x0 += k1;  x1 += ks2 + 4u;
  TFR(13) TFR(15) TFR(26) TFR(6)  x0 += ks2; x1 += k0 + 5u;
#undef TFR
  o0 = x0; o1 = x1;
}

// XLA's ErfInv32 polynomial (math.cc), no fp contraction to match XLA rounding.
__device__ float xla_erfinv(float x) {
#pragma clang fp contract(off)
  float w = -log1pf(-x * x);
  float p;
  if (w < 5.0f) {
    w = w - 2.5f;
    p = 2.81022636e-08f;
    p = 3.43273939e-07f  + p * w;
    p = -3.5233877e-06f  + p * w;
    p = -4.39150654e-06f + p * w;
    p = 0.00021858087f   + p * w;
    p = -0.00125372503f  + p * w;
    p = -0.00417768164f  + p * w;
    p = 0.246640727f     + p * w;
    p = 1.50140941f      + p * w;
  } else {
    w = sqrtf(w) - 3.0f;
    p = -0.000200214257f;
    p = 0.000100950558f + p * w;
    p = 0.00134934322f  + p * w;
    p = -0.00367342844f + p * w;
    p = 0.00573950773f  + p * w;
    p = -0.0076224613f  + p * w;
    p = 0.00943887047f  + p * w;
    p = 1.00167406f     + p * w;
    p = 2.83297682f     + p * w;
  }
  return p * x;
}

// Merged prep: aux weight transposes + rot RNG + m-weight transposes + inv perm.
__global__ void k_prep(const float* __restrict__ mw1, const float* __restrict__ mw2,
                       const float* __restrict__ mws,
                       const float* __restrict__ a1w1, const float* __restrict__ a1w2,
                       const float* __restrict__ a2w1, const float* __restrict__ a2w2,
                       const int* __restrict__ ri,
                       float* __restrict__ rotT, float* __restrict__ wT1,
                       float* __restrict__ wT2, float* __restrict__ wTs,
                       float* __restrict__ auxT, int* __restrict__ inv) {
  int gid = blockIdx.x * 256 + threadIdx.x;
  if (gid < 4 * AUXW) {
    int wsel = gid / AUXW, j = gid % AUXW;
    const float* src = (wsel == 0) ? a1w1 : (wsel == 1) ? a1w2 : (wsel == 2) ? a2w1 : a2w2;
    int co = j / 576, r = j % 576;                 // coalesced read
    auxT[wsel * AUXW + r * 64 + co] = src[j];
    return;
  }
  int g2 = gid - 4 * AUXW;
  if (g2 < 4096) {
    int i = g2;
    unsigned o0, o1, bits;
#if JAX_THREEFRY_PARTITIONABLE
    tf2x32(0u, 42u, 0u, (unsigned)i, o0, o1);
    bits = o0 ^ o1;
#else
    if (i < 2048) { tf2x32(0u, 42u, (unsigned)i, (unsigned)(i + 2048), o0, o1); bits = o0; }
    else          { tf2x32(0u, 42u, (unsigned)(i - 2048), (unsigned)i, o0, o1); bits = o1; }
#endif
    unsigned fb = (bits >> 9) | 0x3f800000u;
    float f = __uint_as_float(fb) - 1.0f;
    const float lo = __uint_as_float(0xBF7FFFFFu);  // nextafter(-1,0)
    float u = fmaxf(lo, f * 2.0f + lo);
    float r = __uint_as_float(0x3FB504F3u) * xla_erfinv(u);  // sqrt(2)*erfinv(u)
    int c = i >> 8, h = (i >> 6) & 3, j = i & 63;
    rotT[(h * 64 + j) * 16 + c] = r;
    return;
  }
  int g3 = g2 - 4096;
  if (g3 < 9216) {
    { int o = g3 / 576; int r = g3 % 576; wT1[r * 16 + o] = mw1[g3]; }
    if (g3 < 2304) { int o = g3 / 144; int r = g3 % 144; wT2[r * 16 + o] = mw2[g3]; }
    if (g3 < 1024) { int o = g3 / 64;  int ci = g3 % 64; wTs[ci * 16 + o] = mws[g3]; }
    return;
  }
  int g4 = g3 - 9216;
  if (g4 < TL) {
    int p = ri[g4];
    if (p < LL) inv[p] = g4;
  }
}

// conv1 (m-block, 64->16 3x3), K-split in 2 halves of 32 ci.
// block = (img n, khalf, 16x16 tile); thread = (co, y-row) over 16-px x-strip.
// Weights register-stationary per 8-ci chunk; partial sums (no bias/relu) to ht0/ht1.
__global__ __launch_bounds__(256) void k_conv1(
    const float* __restrict__ fd1, const float* __restrict__ fd2,
    const float* __restrict__ wT1,
    float* __restrict__ ht0, float* __restrict__ ht1) {
  int blk = blockIdx.x;
  int kh = blk & 1;
  int rest = blk >> 1;
  int n = rest / 49, tile = rest % 49;
  int ty0 = (tile / 7) * 16, tx0 = (tile % 7) * 16;
  const float* in = ((n >> 1) ? fd2 : fd1) + (n & 1) * (C0 * LL) + (kh * 32) * LL;
  float* htk = (kh ? ht1 : ht0) + n * 16 * LL;
  int tid = threadIdx.x;
  int co = tid & 15, yl = tid >> 4;

  __shared__ float sIn[32 * 18 * 20];   // [ci][18 rows][20 pad] halo tile
  __shared__ float sW[288 * 16];        // this half's weights [(ci*9+t)][co]

  // stage weights (contiguous)
  for (int i = tid; i < 288 * 16; i += 256) sW[i] = wT1[kh * 4608 + i];
  // stage input halo tile, zero-padded
  for (int idx = tid; idx < 32 * 18 * 18; idx += 256) {
    int ci = idx / 324, r = idx % 324, iy = r / 18, ix = r % 18;
    int gy = ty0 - 1 + iy, gx = tx0 - 1 + ix;
    float v = 0.f;
    if (gy >= 0 && gy < HH && gx >= 0 && gx < WWW) v = in[ci * LL + gy * WWW + gx];
    sIn[ci * 360 + iy * 20 + ix] = v;
  }
  __syncthreads();

  float acc[16];
#pragma unroll
  for (int p = 0; p < 16; ++p) acc[p] = 0.f;

  for (int cc = 0; cc < 4; ++cc) {   // 8-ci chunks
    float w[8][9];
#pragma unroll
    for (int c8 = 0; c8 < 8; ++c8)
#pragma unroll
      for (int t = 0; t < 9; ++t)
        w[c8][t] = sW[((cc * 8 + c8) * 9 + t) * 16 + co];
#pragma unroll
    for (int c8 = 0; c8 < 8; ++c8) {
      const float* rowb = &sIn[(cc * 8 + c8) * 360 + yl * 20];
#pragma unroll
      for (int dy = 0; dy < 3; ++dy) {
        const float* r = rowb + dy * 20;
        float v[18];
#pragma unroll
        for (int k = 0; k < 18; ++k) v[k] = r[k];
#pragma unroll
        for (int dx = 0; dx < 3; ++dx) {
          float wv = w[c8][dy * 3 + dx];
#pragma unroll
          for (int p = 0; p < 16; ++p) acc[p] = fmaf(v[p + dx], wv, acc[p]);
        }
      }
    }
  }

  int yv = ty0 + yl;
  if (yv < HH) {
    float* op = htk + co * LL + yv * WWW;
#pragma unroll
    for (int g = 0; g < 4; ++g) {
      int xg = tx0 + g * 4;
      if (xg < WWW) {
        float4 s = make_float4(acc[g * 4], acc[g * 4 + 1], acc[g * 4 + 2], acc[g * 4 + 3]);
        *(float4*)&op[xg] = s;
      }
    }
  }
}

// conv2 (16->16 3x3 + b2) + skip (1x1 64->16 + mbs) on h = relu(ht0+ht1+mb1).
// Low-VGPR variant: weights from LDS at use; acc[16] only big per-thread array.
// block = (img n, 8y x 16x tile); 128 threads = (co, yl in 0..7).
__global__ __launch_bounds__(128) void k_conv2(
    const float* __restrict__ fd1, const float* __restrict__ fd2,
    const float* __restrict__ ht0, const float* __restrict__ ht1,
    const float* __restrict__ wT2, const float* __restrict__ mb1,
    const float* __restrict__ mb2, const float* __restrict__ wTs,
    const float* __restrict__ mbs, float* __restrict__ F) {
  int blk = blockIdx.x;
  int n = blk / 91, tile = blk % 91;
  int yt = tile / 7, xt = tile % 7;       // 13 y-tiles x 7 x-tiles
  int ty0 = yt * 8, tx0 = xt * 16;
  int src = n >> 1, b = n & 1;
  const float* in = (src ? fd2 : fd1) + b * (C0 * LL);
  const float* h0 = ht0 + n * 16 * LL;
  const float* h1 = ht1 + n * 16 * LL;
  int tid = threadIdx.x;
  int co = tid & 15, yl = tid >> 4;       // yl 0..7

  __shared__ float sW2[144 * 16];         // [(ci*9+t)][co]
  __shared__ float sWs[64 * 16];          // [ci][co]
  __shared__ float sH[16 * 10 * 20];      // h halo [ci][10 rows][20 pad (18 used)]
  __shared__ float sSkip[16 * 8 * 17];    // skip chunk [ci16][8][17 pad (16 used)]

  for (int i = tid; i < 144 * 16; i += 128) sW2[i] = wT2[i];
  for (int i = tid; i < 64 * 16; i += 128) sWs[i] = wTs[i];
  for (int idx = tid; idx < 16 * 10 * 18; idx += 128) {
    int ci = idx / 180, r = idx % 180, iy = r / 18, ix = r % 18;
    int gy = ty0 - 1 + iy, gx = tx0 - 1 + ix;
    float v = 0.f;
    if (gy >= 0 && gy < HH && gx >= 0 && gx < WWW) {
      int o = ci * LL + gy * WWW + gx;
      v = fmaxf(h0[o] + h1[o] + mb1[ci], 0.f);
    }
    sH[ci * 200 + iy * 20 + ix] = v;
  }
  __syncthreads();

  float acc[16];
  float bias = mb2[co] + mbs[co];
#pragma unroll
  for (int p = 0; p < 16; ++p) acc[p] = bias;

  // conv 3x3 over the 16 h-channels
  for (int ci = 0; ci < 16; ++ci) {
    const float* rowb = &sH[ci * 200 + yl * 20];
#pragma unroll
    for (int dy = 0; dy < 3; ++dy) {
      const float* r = rowb + dy * 20;
      float v[18];
#pragma unroll
      for (int k = 0; k < 18; ++k) v[k] = r[k];
#pragma unroll
      for (int dx = 0; dx < 3; ++dx) {
        float wv = sW2[(ci * 9 + dy * 3 + dx) * 16 + co];
#pragma unroll
        for (int p = 0; p < 16; ++p) acc[p] = fmaf(v[p + dx], wv, acc[p]);
      }
    }
  }

  // skip 1x1 over 64 ci, staged in 4 chunks of 16 ci
  for (int cc = 0; cc < 4; ++cc) {
    __syncthreads();
    for (int idx = tid; idx < 16 * 8 * 16; idx += 128) {
      int ci = idx >> 7, r = idx & 127, iy = r >> 4, ix = r & 15;
      int gy = ty0 + iy, gx = tx0 + ix;
      float v = 0.f;
      if (gy < HH && gx < WWW) v = in[(cc * 16 + ci) * LL + gy * WWW + gx];
      sSkip[(ci * 8 + iy) * 17 + ix] = v;
    }
    __syncthreads();
    for (int c16 = 0; c16 < 16; ++c16) {
      float wv = sWs[(cc * 16 + c16) * 16 + co];
      const float* sv = &sSkip[(c16 * 8 + yl) * 17];
#pragma unroll
      for (int p = 0; p < 16; ++p) acc[p] = fmaf(sv[p], wv, acc[p]);
    }
  }

  int yv = ty0 + yl;
  if (yv < HH) {
    float* Fb = F + (b * TL + src * LL + yv * WWW) * 16 + co;
#pragma unroll
    for (int p = 0; p < 16; ++p) {
      int xv = tx0 + p;
      if (xv < WWW) Fb[xv * 16] = acc[p];
    }
  }
}

// codes in permuted order: code[bh][t'] = argmax over [rv, -rv] at row ri[t']
__global__ __launch_bounds__(256) void k_codes(
    const float* __restrict__ F, const float* __restrict__ rotT,
    const int* __restrict__ ri, unsigned char* __restrict__ codes) {
  int bh = blockIdx.y;
  int b = bh >> 2, h = bh & 3;
  __shared__ float srot[1024];
  int tid = threadIdx.x;
  for (int i = tid; i < 1024; i += 256) srot[i] = rotT[h * 1024 + i];
  __syncthreads();
  int t = blockIdx.x * 256 + tid;
  if (t >= TL) return;
  int pos = ri[t];
  const float* Fr = F + (b * TL + pos) * 16;
  float q[16];
#pragma unroll
  for (int c = 0; c < 16; ++c) q[c] = Fr[c];
  float best = -1e30f; int bi = 0;
  float worst = 1e30f; int wi = 0;
  for (int j = 0; j < 64; ++j) {
    float v = 0.f;
    const float* rp = srot + j * 16;
#pragma unroll
    for (int c = 0; c < 16; ++c) v = fmaf(q[c], rp[c], v);
    if (v > best)  { best = v;  bi = j; }
    if (v < worst) { worst = v; wi = j; }
  }
  int code = (best >= -worst) ? bi : (64 + wi);
  codes[bh * TL + t] = (unsigned char)code;
}

// stable counting sort per (b,h); emit rank_of[t'] and even-parity chunk counts n0
__global__ __launch_bounds__(256) void k_sort(
    const unsigned char* __restrict__ codes,
    int* __restrict__ rank_of, int* __restrict__ n0g) {
  int bh = blockIdx.x;
  const unsigned char* keys = codes + bh * TL;
  __shared__ unsigned short cnt[240][128];
  __shared__ unsigned int totals[128];
  __shared__ unsigned int baseoff[128];
  __shared__ unsigned int n0s[NCHK];
  int tid = threadIdx.x;
  for (int i = tid; i < 240 * 128 / 2; i += 256) ((unsigned int*)cnt)[i] = 0u;
  for (int i = tid; i < NCHK; i += 256) n0s[i] = 0u;
  __syncthreads();
  const int SEG = 84;
  int base = tid * SEG;
  int nloc = (tid < 240) ? (TL - base) : 0;
  if (nloc > SEG) nloc = SEG;
  if (nloc < 0) nloc = 0;
  for (int e = 0; e < nloc; ++e) cnt[tid][keys[base + e]]++;
  __syncthreads();
  if (tid < 128) {
    unsigned int s = 0;
    for (int g = 0; g < 240; ++g) s += cnt[g][tid];
    totals[tid] = s;
  }
  __syncthreads();
  if (tid == 0) {
    unsigned int run = 0;
    for (int c = 0; c < 128; ++c) { baseoff[c] = run; run += totals[c]; }
  }
  __syncthreads();
  if (tid < 128) {
    unsigned int run = baseoff[tid];
    for (int g = 0; g < 240; ++g) {
      unsigned int v = cnt[g][tid];
      cnt[g][tid] = (unsigned short)run;
      run += v;
    }
  }
  __syncthreads();
  for (int e = 0; e < nloc; ++e) {
    int idx = base + e;
    int c = keys[idx];
    int r = cnt[tid][c]++;
    rank_of[bh * TL + idx] = r;
    if (!(idx & 1)) {
      atomicAdd(&n0s[r / CHK], 1u);
      if (r >= TL - NPAD) atomicAdd(&n0s[NCHK - 1], 1u);
    }
  }
  __syncthreads();
  for (int i = tid; i < NCHK; i += 256) n0g[bh * NCHK + i] = (int)n0s[i];
}

// blocks 0..3: rA/rB point-resblock, LDS-staged; block 4: per-batch E scalars.
__global__ __launch_bounds__(576) void k_point(
    const float* __restrict__ fd1, const float* __restrict__ refin,
    const int* __restrict__ ri, const float* __restrict__ auxT,
    const float* __restrict__ a1b1, const float* __restrict__ a1b2,
    const float* __restrict__ a2b1, const float* __restrict__ a2b2,
    const float* __restrict__ F, float* __restrict__ SC) {
  int tid = threadIdx.x;
  if (blockIdx.x == 4) {
#pragma clang fp contract(off)
    int b = tid;
    if (b >= BN) return;
    int j0 = ri[0], jL = ri[LL];
    const float* qA = F + (b * TL + j0) * 16;
    const float* qB = F + (b * TL + jL) * 16;
    float nA = 0.f, nB = 0.f;
    for (int c = 0; c < 16; ++c) { nA += qA[c] * qA[c]; nB += qB[c] * qB[c]; }
    float mA = fmaxf(sqrtf(nA), 5e-5f), mB = fmaxf(sqrtf(nB), 5e-5f);
    float d00 = 0.f, d01 = 0.f, d10 = 0.f, d11 = 0.f;
    for (int c = 0; c < 16; ++c) {
      float kAc = qA[c] / mA, kBc = qB[c] / mB;
      d00 += qA[c] * kAc; d01 += qA[c] * kBc;
      d10 += qB[c] * kAc; d11 += qB[c] * kBc;
    }
    float zA = (j0 < LL) ? 0.01f : 0.99f;
    float zB = (jL < LL) ? 0.01f : 0.99f;
    float* sc = SC + b * 136;
    sc[0] = expf(d00) * zA; sc[1] = expf(d01) * zB;
    sc[2] = expf(d10) * zA; sc[3] = expf(d11) * zB;
    return;
  }
  int b = blockIdx.x & 1, which = blockIdx.x >> 1;
  int pos = ri[which * LL];
  const float *in, *w1T, *b1, *w2T, *b2;
  int sp;
  if (pos < LL) {
    in = fd1 + b * C0 * LL; w1T = auxT; b1 = a1b1; w2T = auxT + AUXW; b2 = a1b2; sp = pos;
  } else {
    in = refin + b * C0 * LL; w1T = auxT + 2 * AUXW; b1 = a2b1; w2T = auxT + 3 * AUXW;
    b2 = a2b2; sp = pos - LL;
  }
  int y = sp / WWW, x = sp % WWW;

  __shared__ float sPatch[64][25];
  __shared__ float sW[144 * 64];
  __shared__ float sH[9][64];
  __shared__ float sPart[9][64];

  for (int idx = tid; idx < 64 * 25; idx += 576) {
    int ci = idx / 25, pp = idx % 25;
    int gy = y - 2 + pp / 5, gx = x - 2 + pp % 5;
    float v = 0.f;
    if (gy >= 0 && gy < HH && gx >= 0 && gx < WWW) v = in[ci * LL + gy * WWW + gx];
    sPatch[ci][pp] = v;
  }

  int p = tid / 64, ch = tid & 63;
  int p3 = p / 3, pm = p % 3;
  int yy = y + p3 - 1, xx = x + pm - 1;
  bool inb = (yy >= 0) && (yy < HH) && (xx >= 0) && (xx < WWW);

  float acc0 = 0.f, acc1 = 0.f;
  for (int cc = 0; cc < 4; ++cc) {
    __syncthreads();
    for (int i = tid; i < 144 * 64; i += 576) sW[i] = w1T[cc * 9216 + i];
    __syncthreads();
    if (inb) {
#pragma unroll
      for (int ci = 0; ci < 16; ++ci) {
        const float* wp = &sW[ci * 9 * 64 + ch];
        const float* pr = &sPatch[cc * 16 + ci][0];
#pragma unroll
        for (int t = 0; t < 9; ++t) {
          float v = pr[(p3 + t / 3) * 5 + (pm + t % 3)];
          if (ci & 1) acc1 = fmaf(v, wp[t * 64], acc1);
          else        acc0 = fmaf(v, wp[t * 64], acc0);
        }
      }
    }
  }
  sH[p][ch] = inb ? fmaxf(acc0 + acc1 + b1[ch], 0.f) : 0.f;
  __syncthreads();

  {
    float part = 0.f;
    const float* wbase = w2T + p * 64 + ch;
    for (int ci = 0; ci < 64; ++ci) part = fmaf(sH[p][ci], wbase[ci * 9 * 64], part);
    sPart[p][ch] = part;
  }
  __syncthreads();
  if (tid < 64) {
    int co = tid;
    float a = in[co * LL + y * WWW + x] + b2[co];
#pragma unroll
    for (int g = 0; g < 9; ++g) a += sPart[g][co];
    SC[b * 136 + 4 + which * 64 + co] = a;
  }
}

// per (b, t'): alpha/beta = hash-summed numerators over hash-summed denominators
__global__ void k_ab(const int* __restrict__ rank_of, const int* __restrict__ n0,
                     const float* __restrict__ SC, float* __restrict__ AB) {
  int gid = blockIdx.x * 256 + threadIdx.x;
  if (gid >= BN * TL) return;
  int b = gid / TL, t = gid % TL;
  int si = t & 1;
  float e0 = SC[b * 136 + si * 2 + 0];
  float e1 = SC[b * 136 + si * 2 + 1];
  float s0 = 0.f, s1 = 0.f;
  for (int h = 0; h < 4; ++h) {
    int r = rank_of[(b * 4 + h) * TL + t];
    int k = r / CHK;
    int km = (k == 0) ? NCHK - 1 : k - 1;
    int kp = (k == NCHK - 1) ? 0 : k + 1;
    const int* nb = n0 + (b * 4 + h) * NCHK;
    int W0 = nb[k] + nb[km] + nb[kp];
    s0 += (float)W0 * e0;
    s1 += (float)(WINR - W0) * e1;
  }
  float invd = 1.f / (s0 + s1);
  AB[(b * TL + t) * 2 + 0] = s0 * invd;
  AB[(b * TL + t) * 2 + 1] = s1 * invd;
}

// out[b][c][p] = alpha*rA[c] + beta*rB[c], p < L
__global__ __launch_bounds__(256) void k_out(
    const int* __restrict__ inv, const float* __restrict__ AB,
    const float* __restrict__ SC, float* __restrict__ out) {
  int b = blockIdx.y;
  int p = blockIdx.x * 256 + threadIdx.x;
  if (p >= LL) return;
  int t = inv[p];
  float al = AB[(b * TL + t) * 2 + 0];
  float be = AB[(b * TL + t) * 2 + 1];
  const float* rA = SC + b * 136 + 4;
  const float* rB = rA + 64;
  float* o = out + b * C0 * LL + p;
#pragma unroll
  for (int c = 0; c < 64; ++c) o[c * LL] = al * rA[c] + be * rB[c];
}

}  // namespace

extern "C" void kernel_launch(void* const* d_in, const int* in_sizes, int n_in,
                              void* d_out, int out_size, void* d_ws, size_t ws_size,
                              hipStream_t stream) {
  const float* fd1  = (const float*)d_in[0];
  const float* fd2  = (const float*)d_in[1];
  const float* reff = (const float*)d_in[2];
  const int*   ri   = (const int*)d_in[3];
  const float* mw1  = (const float*)d_in[4];
  const float* mb1  = (const float*)d_in[5];
  const float* mw2  = (const float*)d_in[6];
  const float* mb2  = (const float*)d_in[7];
  const float* mws  = (const float*)d_in[8];
  const float* mbs  = (const float*)d_in[9];
  const float* a1w1 = (const float*)d_in[10];
  const float* a1b1 = (const float*)d_in[11];
  const float* a1w2 = (const float*)d_in[12];
  const float* a1b2 = (const float*)d_in[13];
  const float* a2w1 = (const float*)d_in[14];
  const float* a2b1 = (const float*)d_in[15];
  const float* a2w2 = (const float*)d_in[16];
  const float* a2b2 = (const float*)d_in[17];

  float* ws = (float*)d_ws;
  float* rotT = ws + OFF_ROT;
  float* wT1  = ws + OFF_WT1;
  float* wT2  = ws + OFF_WT2;
  float* wTs  = ws + OFF_WTS;
  float* ht0  = ws + OFF_HT0;
  float* ht1  = ws + OFF_HT1;
  float* F    = ws + OFF_F;
  float* SC   = ws + OFF_SC;
  float* AB   = ws + OFF_AB;
  unsigned char* codes = (unsigned char*)(ws + OFF_CODE);
  int* rank_of = (int*)(ws + OFF_RANK);
  int* n0      = (int*)(ws + OFF_N0);
  int* invp    = (int*)(ws + OFF_INV);
  float* auxT  = ws + OFF_AUX;

  k_prep<<<dim3(707), dim3(256), 0, stream>>>(mw1, mw2, mws, a1w1, a1w2, a2w1, a2w2,
                                              ri, rotT, wT1, wT2, wTs, auxT, invp);
  k_conv1<<<dim3(392), dim3(256), 0, stream>>>(fd1, fd2, wT1, ht0, ht1);
  k_conv2<<<dim3(364), dim3(128), 0, stream>>>(fd1, fd2, ht0, ht1, wT2, mb1, mb2,
                                               wTs, mbs, F);
  k_codes<<<dim3(79, 8), dim3(256), 0, stream>>>(F, rotT, ri, codes);
  k_sort<<<dim3(8), dim3(256), 0, stream>>>(codes, rank_of, n0);
  k_point<<<dim3(5), dim3(576), 0, stream>>>(fd1, reff, ri, auxT, a1b1, a1b2,
                                             a2b1, a2b2, F, SC);
  k_ab<<<dim3(157), dim3(256), 0, stream>>>(rank_of, n0, SC, AB);
  k_out<<<dim3(40, 2), dim3(256), 0, stream>>>(invp, AB, SC, (float*)d_out);
}

// Round 5
// 156.964 us; speedup vs baseline: 3.3851x; 1.1639x over previous
//
#include <hip/hip_runtime.h>

// Flip to 0 if absmax fails large: selects legacy (non-partitionable) JAX threefry stream.
#define JAX_THREEFRY_PARTITIONABLE 1

namespace {

constexpr int BN   = 2;      // batch
constexpr int C0   = 64;
constexpr int HH   = 100;
constexpr int WWW  = 100;
constexpr int LL   = 10000;  // H*W
constexpr int TL   = 20000;  // 2L
constexpr int CHK  = 144;
constexpr int NCHK = 139;    // (TL+16)/144
constexpr int NPAD = 16;
constexpr int WINR = 432;    // 3*144

// ws layout in float slots
constexpr int OFF_ROT  = 0;                    // rotT [4][64][16]
constexpr int OFF_WT1  = OFF_ROT + 4096;       // [64*9][16]
constexpr int OFF_WT2  = OFF_WT1 + 9216;       // [16*9][16]
constexpr int OFF_WTS  = OFF_WT2 + 2304;       // [64][16]
constexpr int OFF_HT0  = OFF_WTS + 1024;       // conv1 partial kq=0 [4][16][10000]
constexpr int OFF_HT1  = OFF_HT0 + 640000;     // kq=1
constexpr int OFF_HT2  = OFF_HT1 + 640000;     // kq=2
constexpr int OFF_HT3  = OFF_HT2 + 640000;     // kq=3
constexpr int OFF_F    = OFF_HT3 + 640000;     // F [2][20000][16]
constexpr int OFF_SC   = OFF_F + 640000;       // SC [2][136]
constexpr int OFF_AB   = OFF_SC + 272;         // AB [2][20000][2]
constexpr int OFF_CODE = OFF_AB + 80000;       // codes u8 [8][20000]
constexpr int OFF_RANK = OFF_CODE + 40000;     // rank int [8][20000]
constexpr int OFF_N0   = OFF_RANK + 160000;    // n0 int [8][139]
constexpr int OFF_INV  = OFF_N0 + 1112;        // inv int [10000]
constexpr int OFF_AUX  = OFF_INV + 10000;      // auxT: 4 x [576][64]

constexpr int AUXW = 36864;  // 64*64*9

__device__ __forceinline__ unsigned rotl32(unsigned v, int r) {
  return (v << r) | (v >> (32 - r));
}

// JAX threefry2x32, 20 rounds, key injection every 4.
__device__ void tf2x32(unsigned k0, unsigned k1, unsigned x0, unsigned x1,
                       unsigned& o0, unsigned& o1) {
  unsigned ks2 = k0 ^ k1 ^ 0x1BD11BDAu;
  x0 += k0; x1 += k1;
#define TFR(r) { x0 += x1; x1 = rotl32(x1, r); x1 ^= x0; }
  TFR(13) TFR(15) TFR(26) TFR(6)  x0 += k1;  x1 += ks2 + 1u;
  TFR(17) TFR(29) TFR(16) TFR(24) x0 += ks2; x1 += k0 + 2u;
  TFR(13) TFR(15) TFR(26) TFR(6)  x0 += k0;  x1 += k1 + 3u;
  TFR(17) TFR(29) TFR(16) TFR(24) x0 += k1;  x1 += ks2 + 4u;
  TFR(13) TFR(15) TFR(26) TFR(6)  x0 += ks2; x1 += k0 + 5u;
#undef TFR
  o0 = x0; o1 = x1;
}

// XLA's ErfInv32 polynomial (math.cc), no fp contraction to match XLA rounding.
__device__ float xla_erfinv(float x) {
#pragma clang fp contract(off)
  float w = -log1pf(-x * x);
  float p;
  if (w < 5.0f) {
    w = w - 2.5f;
    p = 2.81022636e-08f;
    p = 3.43273939e-07f  + p * w;
    p = -3.5233877e-06f  + p * w;
    p = -4.39150654e-06f + p * w;
    p = 0.00021858087f   + p * w;
    p = -0.00125372503f  + p * w;
    p = -0.00417768164f  + p * w;
    p = 0.246640727f     + p * w;
    p = 1.50140941f      + p * w;
  } else {
    w = sqrtf(w) - 3.0f;
    p = -0.000200214257f;
    p = 0.000100950558f + p * w;
    p = 0.00134934322f  + p * w;
    p = -0.00367342844f + p * w;
    p = 0.00573950773f  + p * w;
    p = -0.0076224613f  + p * w;
    p = 0.00943887047f  + p * w;
    p = 1.00167406f     + p * w;
    p = 2.83297682f     + p * w;
  }
  return p * x;
}

// Merged prep: aux weight transposes + rot RNG + m-weight transposes + inv perm.
__global__ void k_prep(const float* __restrict__ mw1, const float* __restrict__ mw2,
                       const float* __restrict__ mws,
                       const float* __restrict__ a1w1, const float* __restrict__ a1w2,
                       const float* __restrict__ a2w1, const float* __restrict__ a2w2,
                       const int* __restrict__ ri,
                       float* __restrict__ rotT, float* __restrict__ wT1,
                       float* __restrict__ wT2, float* __restrict__ wTs,
                       float* __restrict__ auxT, int* __restrict__ inv) {
  int gid = blockIdx.x * 256 + threadIdx.x;
  if (gid < 4 * AUXW) {
    int wsel = gid / AUXW, j = gid % AUXW;
    const float* src = (wsel == 0) ? a1w1 : (wsel == 1) ? a1w2 : (wsel == 2) ? a2w1 : a2w2;
    int co = j / 576, r = j % 576;                 // coalesced read
    auxT[wsel * AUXW + r * 64 + co] = src[j];
    return;
  }
  int g2 = gid - 4 * AUXW;
  if (g2 < 4096) {
    int i = g2;
    unsigned o0, o1, bits;
#if JAX_THREEFRY_PARTITIONABLE
    tf2x32(0u, 42u, 0u, (unsigned)i, o0, o1);
    bits = o0 ^ o1;
#else
    if (i < 2048) { tf2x32(0u, 42u, (unsigned)i, (unsigned)(i + 2048), o0, o1); bits = o0; }
    else          { tf2x32(0u, 42u, (unsigned)(i - 2048), (unsigned)i, o0, o1); bits = o1; }
#endif
    unsigned fb = (bits >> 9) | 0x3f800000u;
    float f = __uint_as_float(fb) - 1.0f;
    const float lo = __uint_as_float(0xBF7FFFFFu);  // nextafter(-1,0)
    float u = fmaxf(lo, f * 2.0f + lo);
    float r = __uint_as_float(0x3FB504F3u) * xla_erfinv(u);  // sqrt(2)*erfinv(u)
    int c = i >> 8, h = (i >> 6) & 3, j = i & 63;
    rotT[(h * 64 + j) * 16 + c] = r;
    return;
  }
  int g3 = g2 - 4096;
  if (g3 < 9216) {
    { int o = g3 / 576; int r = g3 % 576; wT1[r * 16 + o] = mw1[g3]; }
    if (g3 < 2304) { int o = g3 / 144; int r = g3 % 144; wT2[r * 16 + o] = mw2[g3]; }
    if (g3 < 1024) { int o = g3 / 64;  int ci = g3 % 64; wTs[ci * 16 + o] = mws[g3]; }
    return;
  }
  int g4 = g3 - 9216;
  if (g4 < TL) {
    int p = ri[g4];
    if (p < LL) inv[p] = g4;
  }
}

// conv1 (m-block, 64->16 3x3), K-split in 4 quarters of 16 ci.
// block = (img n, kq, 16x16 tile); thread = (co, y-row) over 16-px x-strip.
// 4-ci weight chunks register-stationary; partial sums (no bias/relu) to ht[kq].
__global__ __launch_bounds__(256) void k_conv1(
    const float* __restrict__ fd1, const float* __restrict__ fd2,
    const float* __restrict__ wT1,
    float* __restrict__ ht0, float* __restrict__ ht1,
    float* __restrict__ ht2, float* __restrict__ ht3) {
  int blk = blockIdx.x;
  int kq = blk & 3;
  int rest = blk >> 2;
  int n = rest / 49, tile = rest % 49;
  int ty0 = (tile / 7) * 16, tx0 = (tile % 7) * 16;
  const float* in = ((n >> 1) ? fd2 : fd1) + (n & 1) * (C0 * LL) + (kq * 16) * LL;
  float* htk = ((kq == 0) ? ht0 : (kq == 1) ? ht1 : (kq == 2) ? ht2 : ht3) + n * 16 * LL;
  int tid = threadIdx.x;
  int co = tid & 15, yl = tid >> 4;

  __shared__ float sIn[16 * 18 * 20];   // [ci][18 rows][20 pad] halo tile (23KB)
  __shared__ float sW[144 * 16];        // this quarter's weights [(ci*9+t)][co] (9.2KB)

  for (int i = tid; i < 144 * 16; i += 256) sW[i] = wT1[kq * 2304 + i];
  for (int idx = tid; idx < 16 * 18 * 18; idx += 256) {
    int ci = idx / 324, r = idx % 324, iy = r / 18, ix = r % 18;
    int gy = ty0 - 1 + iy, gx = tx0 - 1 + ix;
    float v = 0.f;
    if (gy >= 0 && gy < HH && gx >= 0 && gx < WWW) v = in[ci * LL + gy * WWW + gx];
    sIn[ci * 360 + iy * 20 + ix] = v;
  }
  __syncthreads();

  float acc[16];
#pragma unroll
  for (int p = 0; p < 16; ++p) acc[p] = 0.f;

  for (int cc = 0; cc < 4; ++cc) {   // 4-ci chunks (keeps VGPR <= ~128)
    float w[4][9];
#pragma unroll
    for (int c4 = 0; c4 < 4; ++c4)
#pragma unroll
      for (int t = 0; t < 9; ++t)
        w[c4][t] = sW[((cc * 4 + c4) * 9 + t) * 16 + co];
#pragma unroll
    for (int c4 = 0; c4 < 4; ++c4) {
      const float* rowb = &sIn[(cc * 4 + c4) * 360 + yl * 20];
#pragma unroll
      for (int dy = 0; dy < 3; ++dy) {
        const float* r = rowb + dy * 20;
        float v[18];
#pragma unroll
        for (int k = 0; k < 18; ++k) v[k] = r[k];
#pragma unroll
        for (int dx = 0; dx < 3; ++dx) {
          float wv = w[c4][dy * 3 + dx];
#pragma unroll
          for (int p = 0; p < 16; ++p) acc[p] = fmaf(v[p + dx], wv, acc[p]);
        }
      }
    }
  }

  int yv = ty0 + yl;
  if (yv < HH) {
    float* op = htk + co * LL + yv * WWW;
#pragma unroll
    for (int g = 0; g < 4; ++g) {
      int xg = tx0 + g * 4;
      if (xg < WWW) {
        float4 s = make_float4(acc[g * 4], acc[g * 4 + 1], acc[g * 4 + 2], acc[g * 4 + 3]);
        *(float4*)&op[xg] = s;
      }
    }
  }
}

// conv2 (16->16 3x3 + b2) + skip (1x1 64->16 + mbs) on h = relu(sum(ht)+mb1).
// Low-VGPR variant: weights from LDS at use; acc[16] only big per-thread array.
// block = (img n, 8y x 16x tile); 128 threads = (co, yl in 0..7).
__global__ __launch_bounds__(128) void k_conv2(
    const float* __restrict__ fd1, const float* __restrict__ fd2,
    const float* __restrict__ ht0, const float* __restrict__ ht1,
    const float* __restrict__ ht2, const float* __restrict__ ht3,
    const float* __restrict__ wT2, const float* __restrict__ mb1,
    const float* __restrict__ mb2, const float* __restrict__ wTs,
    const float* __restrict__ mbs, float* __restrict__ F) {
  int blk = blockIdx.x;
  int n = blk / 91, tile = blk % 91;
  int yt = tile / 7, xt = tile % 7;       // 13 y-tiles x 7 x-tiles
  int ty0 = yt * 8, tx0 = xt * 16;
  int src = n >> 1, b = n & 1;
  const float* in = (src ? fd2 : fd1) + b * (C0 * LL);
  const float* h0 = ht0 + n * 16 * LL;
  const float* h1 = ht1 + n * 16 * LL;
  const float* h2 = ht2 + n * 16 * LL;
  const float* h3 = ht3 + n * 16 * LL;
  int tid = threadIdx.x;
  int co = tid & 15, yl = tid >> 4;       // yl 0..7

  __shared__ float sW2[144 * 16];         // [(ci*9+t)][co]
  __shared__ float sWs[64 * 16];          // [ci][co]
  __shared__ float sH[16 * 10 * 20];      // h halo [ci][10 rows][20 pad (18 used)]
  __shared__ float sSkip[16 * 8 * 17];    // skip chunk [ci16][8][17 pad (16 used)]

  for (int i = tid; i < 144 * 16; i += 128) sW2[i] = wT2[i];
  for (int i = tid; i < 64 * 16; i += 128) sWs[i] = wTs[i];
  for (int idx = tid; idx < 16 * 10 * 18; idx += 128) {
    int ci = idx / 180, r = idx % 180, iy = r / 18, ix = r % 18;
    int gy = ty0 - 1 + iy, gx = tx0 - 1 + ix;
    float v = 0.f;
    if (gy >= 0 && gy < HH && gx >= 0 && gx < WWW) {
      int o = ci * LL + gy * WWW + gx;
      v = fmaxf(h0[o] + h1[o] + h2[o] + h3[o] + mb1[ci], 0.f);
    }
    sH[ci * 200 + iy * 20 + ix] = v;
  }
  __syncthreads();

  float acc[16];
  float bias = mb2[co] + mbs[co];
#pragma unroll
  for (int p = 0; p < 16; ++p) acc[p] = bias;

  // conv 3x3 over the 16 h-channels
  for (int ci = 0; ci < 16; ++ci) {
    const float* rowb = &sH[ci * 200 + yl * 20];
#pragma unroll
    for (int dy = 0; dy < 3; ++dy) {
      const float* r = rowb + dy * 20;
      float v[18];
#pragma unroll
      for (int k = 0; k < 18; ++k) v[k] = r[k];
#pragma unroll
      for (int dx = 0; dx < 3; ++dx) {
        float wv = sW2[(ci * 9 + dy * 3 + dx) * 16 + co];
#pragma unroll
        for (int p = 0; p < 16; ++p) acc[p] = fmaf(v[p + dx], wv, acc[p]);
      }
    }
  }

  // skip 1x1 over 64 ci, staged in 4 chunks of 16 ci
  for (int cc = 0; cc < 4; ++cc) {
    __syncthreads();
    for (int idx = tid; idx < 16 * 8 * 16; idx += 128) {
      int ci = idx >> 7, r = idx & 127, iy = r >> 4, ix = r & 15;
      int gy = ty0 + iy, gx = tx0 + ix;
      float v = 0.f;
      if (gy < HH && gx < WWW) v = in[(cc * 16 + ci) * LL + gy * WWW + gx];
      sSkip[(ci * 8 + iy) * 17 + ix] = v;
    }
    __syncthreads();
    for (int c16 = 0; c16 < 16; ++c16) {
      float wv = sWs[(cc * 16 + c16) * 16 + co];
      const float* sv = &sSkip[(c16 * 8 + yl) * 17];
#pragma unroll
      for (int p = 0; p < 16; ++p) acc[p] = fmaf(sv[p], wv, acc[p]);
    }
  }

  int yv = ty0 + yl;
  if (yv < HH) {
    float* Fb = F + (b * TL + src * LL + yv * WWW) * 16 + co;
#pragma unroll
    for (int p = 0; p < 16; ++p) {
      int xv = tx0 + p;
      if (xv < WWW) Fb[xv * 16] = acc[p];
    }
  }
}

// codes in permuted order: code[bh][t'] = argmax over [rv, -rv] at row ri[t']
__global__ __launch_bounds__(256) void k_codes(
    const float* __restrict__ F, const float* __restrict__ rotT,
    const int* __restrict__ ri, unsigned char* __restrict__ codes) {
  int bh = blockIdx.y;
  int b = bh >> 2, h = bh & 3;
  __shared__ float srot[1024];
  int tid = threadIdx.x;
  for (int i = tid; i < 1024; i += 256) srot[i] = rotT[h * 1024 + i];
  __syncthreads();
  int t = blockIdx.x * 256 + tid;
  if (t >= TL) return;
  int pos = ri[t];
  const float* Fr = F + (b * TL + pos) * 16;
  float q[16];
#pragma unroll
  for (int c = 0; c < 16; ++c) q[c] = Fr[c];
  float best = -1e30f; int bi = 0;
  float worst = 1e30f; int wi = 0;
  for (int j = 0; j < 64; ++j) {
    float v = 0.f;
    const float* rp = srot + j * 16;
#pragma unroll
    for (int c = 0; c < 16; ++c) v = fmaf(q[c], rp[c], v);
    if (v > best)  { best = v;  bi = j; }
    if (v < worst) { worst = v; wi = j; }
  }
  int code = (best >= -worst) ? bi : (64 + wi);
  codes[bh * TL + t] = (unsigned char)code;
}

// stable counting sort per (b,h); emit rank_of[t'] and even-parity chunk counts n0
__global__ __launch_bounds__(256) void k_sort(
    const unsigned char* __restrict__ codes,
    int* __restrict__ rank_of, int* __restrict__ n0g) {
  int bh = blockIdx.x;
  const unsigned char* keys = codes + bh * TL;
  __shared__ unsigned short cnt[240][128];
  __shared__ unsigned int totals[128];
  __shared__ unsigned int baseoff[128];
  __shared__ unsigned int n0s[NCHK];
  int tid = threadIdx.x;
  for (int i = tid; i < 240 * 128 / 2; i += 256) ((unsigned int*)cnt)[i] = 0u;
  for (int i = tid; i < NCHK; i += 256) n0s[i] = 0u;
  __syncthreads();
  const int SEG = 84;
  int base = tid * SEG;
  int nloc = (tid < 240) ? (TL - base) : 0;
  if (nloc > SEG) nloc = SEG;
  if (nloc < 0) nloc = 0;
  for (int e = 0; e < nloc; ++e) cnt[tid][keys[base + e]]++;
  __syncthreads();
  if (tid < 128) {
    unsigned int s = 0;
    for (int g = 0; g < 240; ++g) s += cnt[g][tid];
    totals[tid] = s;
  }
  __syncthreads();
  if (tid == 0) {
    unsigned int run = 0;
    for (int c = 0; c < 128; ++c) { baseoff[c] = run; run += totals[c]; }
  }
  __syncthreads();
  if (tid < 128) {
    unsigned int run = baseoff[tid];
    for (int g = 0; g < 240; ++g) {
      unsigned int v = cnt[g][tid];
      cnt[g][tid] = (unsigned short)run;
      run += v;
    }
  }
  __syncthreads();
  for (int e = 0; e < nloc; ++e) {
    int idx = base + e;
    int c = keys[idx];
    int r = cnt[tid][c]++;
    rank_of[bh * TL + idx] = r;
    if (!(idx & 1)) {
      atomicAdd(&n0s[r / CHK], 1u);
      if (r >= TL - NPAD) atomicAdd(&n0s[NCHK - 1], 1u);
    }
  }
  __syncthreads();
  for (int i = tid; i < NCHK; i += 256) n0g[bh * NCHK + i] = (int)n0s[i];
}

// blocks 0..3: rA/rB point-resblock, LDS-staged; block 4: per-batch E scalars.
__global__ __launch_bounds__(576) void k_point(
    const float* __restrict__ fd1, const float* __restrict__ refin,
    const int* __restrict__ ri, const float* __restrict__ auxT,
    const float* __restrict__ a1b1, const float* __restrict__ a1b2,
    const float* __restrict__ a2b1, const float* __restrict__ a2b2,
    const float* __restrict__ F, float* __restrict__ SC) {
  int tid = threadIdx.x;
  if (blockIdx.x == 4) {
#pragma clang fp contract(off)
    int b = tid;
    if (b >= BN) return;
    int j0 = ri[0], jL = ri[LL];
    const float* qA = F + (b * TL + j0) * 16;
    const float* qB = F + (b * TL + jL) * 16;
    float nA = 0.f, nB = 0.f;
    for (int c = 0; c < 16; ++c) { nA += qA[c] * qA[c]; nB += qB[c] * qB[c]; }
    float mA = fmaxf(sqrtf(nA), 5e-5f), mB = fmaxf(sqrtf(nB), 5e-5f);
    float d00 = 0.f, d01 = 0.f, d10 = 0.f, d11 = 0.f;
    for (int c = 0; c < 16; ++c) {
      float kAc = qA[c] / mA, kBc = qB[c] / mB;
      d00 += qA[c] * kAc; d01 += qA[c] * kBc;
      d10 += qB[c] * kAc; d11 += qB[c] * kBc;
    }
    float zA = (j0 < LL) ? 0.01f : 0.99f;
    float zB = (jL < LL) ? 0.01f : 0.99f;
    float* sc = SC + b * 136;
    sc[0] = expf(d00) * zA; sc[1] = expf(d01) * zB;
    sc[2] = expf(d10) * zA; sc[3] = expf(d11) * zB;
    return;
  }
  int b = blockIdx.x & 1, which = blockIdx.x >> 1;
  int pos = ri[which * LL];
  const float *in, *w1T, *b1, *w2T, *b2;
  int sp;
  if (pos < LL) {
    in = fd1 + b * C0 * LL; w1T = auxT; b1 = a1b1; w2T = auxT + AUXW; b2 = a1b2; sp = pos;
  } else {
    in = refin + b * C0 * LL; w1T = auxT + 2 * AUXW; b1 = a2b1; w2T = auxT + 3 * AUXW;
    b2 = a2b2; sp = pos - LL;
  }
  int y = sp / WWW, x = sp % WWW;

  __shared__ float sPatch[64][25];
  __shared__ float sW[144 * 64];
  __shared__ float sH[9][64];
  __shared__ float sPart[9][64];

  for (int idx = tid; idx < 64 * 25; idx += 576) {
    int ci = idx / 25, pp = idx % 25;
    int gy = y - 2 + pp / 5, gx = x - 2 + pp % 5;
    float v = 0.f;
    if (gy >= 0 && gy < HH && gx >= 0 && gx < WWW) v = in[ci * LL + gy * WWW + gx];
    sPatch[ci][pp] = v;
  }

  int p = tid / 64, ch = tid & 63;
  int p3 = p / 3, pm = p % 3;
  int yy = y + p3 - 1, xx = x + pm - 1;
  bool inb = (yy >= 0) && (yy < HH) && (xx >= 0) && (xx < WWW);

  float acc0 = 0.f, acc1 = 0.f;
  for (int cc = 0; cc < 4; ++cc) {
    __syncthreads();
    for (int i = tid; i < 144 * 64; i += 576) sW[i] = w1T[cc * 9216 + i];
    __syncthreads();
    if (inb) {
#pragma unroll
      for (int ci = 0; ci < 16; ++ci) {
        const float* wp = &sW[ci * 9 * 64 + ch];
        const float* pr = &sPatch[cc * 16 + ci][0];
#pragma unroll
        for (int t = 0; t < 9; ++t) {
          float v = pr[(p3 + t / 3) * 5 + (pm + t % 3)];
          if (ci & 1) acc1 = fmaf(v, wp[t * 64], acc1);
          else        acc0 = fmaf(v, wp[t * 64], acc0);
        }
      }
    }
  }
  sH[p][ch] = inb ? fmaxf(acc0 + acc1 + b1[ch], 0.f) : 0.f;
  __syncthreads();

  {
    float part = 0.f;
    const float* wbase = w2T + p * 64 + ch;
    for (int ci = 0; ci < 64; ++ci) part = fmaf(sH[p][ci], wbase[ci * 9 * 64], part);
    sPart[p][ch] = part;
  }
  __syncthreads();
  if (tid < 64) {
    int co = tid;
    float a = in[co * LL + y * WWW + x] + b2[co];
#pragma unroll
    for (int g = 0; g < 9; ++g) a += sPart[g][co];
    SC[b * 136 + 4 + which * 64 + co] = a;
  }
}

// per (b, t'): alpha/beta = hash-summed numerators over hash-summed denominators
__global__ void k_ab(const int* __restrict__ rank_of, const int* __restrict__ n0,
                     const float* __restrict__ SC, float* __restrict__ AB) {
  int gid = blockIdx.x * 256 + threadIdx.x;
  if (gid >= BN * TL) return;
  int b = gid / TL, t = gid % TL;
  int si = t & 1;
  float e0 = SC[b * 136 + si * 2 + 0];
  float e1 = SC[b * 136 + si * 2 + 1];
  float s0 = 0.f, s1 = 0.f;
  for (int h = 0; h < 4; ++h) {
    int r = rank_of[(b * 4 + h) * TL + t];
    int k = r / CHK;
    int km = (k == 0) ? NCHK - 1 : k - 1;
    int kp = (k == NCHK - 1) ? 0 : k + 1;
    const int* nb = n0 + (b * 4 + h) * NCHK;
    int W0 = nb[k] + nb[km] + nb[kp];
    s0 += (float)W0 * e0;
    s1 += (float)(WINR - W0) * e1;
  }
  float invd = 1.f / (s0 + s1);
  AB[(b * TL + t) * 2 + 0] = s0 * invd;
  AB[(b * TL + t) * 2 + 1] = s1 * invd;
}

// out[b][c][p] = alpha*rA[c] + beta*rB[c], p < L
__global__ __launch_bounds__(256) void k_out(
    const int* __restrict__ inv, const float* __restrict__ AB,
    const float* __restrict__ SC, float* __restrict__ out) {
  int b = blockIdx.y;
  int p = blockIdx.x * 256 + threadIdx.x;
  if (p >= LL) return;
  int t = inv[p];
  float al = AB[(b * TL + t) * 2 + 0];
  float be = AB[(b * TL + t) * 2 + 1];
  const float* rA = SC + b * 136 + 4;
  const float* rB = rA + 64;
  float* o = out + b * C0 * LL + p;
#pragma unroll
  for (int c = 0; c < 64; ++c) o[c * LL] = al * rA[c] + be * rB[c];
}

}  // namespace

extern "C" void kernel_launch(void* const* d_in, const int* in_sizes, int n_in,
                              void* d_out, int out_size, void* d_ws, size_t ws_size,
                              hipStream_t stream) {
  const float* fd1  = (const float*)d_in[0];
  const float* fd2  = (const float*)d_in[1];
  const float* reff = (const float*)d_in[2];
  const int*   ri   = (const int*)d_in[3];
  const float* mw1  = (const float*)d_in[4];
  const float* mb1  = (const float*)d_in[5];
  const float* mw2  = (const float*)d_in[6];
  const float* mb2  = (const float*)d_in[7];
  const float* mws  = (const float*)d_in[8];
  const float* mbs  = (const float*)d_in[9];
  const float* a1w1 = (const float*)d_in[10];
  const float* a1b1 = (const float*)d_in[11];
  const float* a1w2 = (const float*)d_in[12];
  const float* a1b2 = (const float*)d_in[13];
  const float* a2w1 = (const float*)d_in[14];
  const float* a2b1 = (const float*)d_in[15];
  const float* a2w2 = (const float*)d_in[16];
  const float* a2b2 = (const float*)d_in[17];

  float* ws = (float*)d_ws;
  float* rotT = ws + OFF_ROT;
  float* wT1  = ws + OFF_WT1;
  float* wT2  = ws + OFF_WT2;
  float* wTs  = ws + OFF_WTS;
  float* ht0  = ws + OFF_HT0;
  float* ht1  = ws + OFF_HT1;
  float* ht2  = ws + OFF_HT2;
  float* ht3  = ws + OFF_HT3;
  float* F    = ws + OFF_F;
  float* SC   = ws + OFF_SC;
  float* AB   = ws + OFF_AB;
  unsigned char* codes = (unsigned char*)(ws + OFF_CODE);
  int* rank_of = (int*)(ws + OFF_RANK);
  int* n0      = (int*)(ws + OFF_N0);
  int* invp    = (int*)(ws + OFF_INV);
  float* auxT  = ws + OFF_AUX;

  k_prep<<<dim3(707), dim3(256), 0, stream>>>(mw1, mw2, mws, a1w1, a1w2, a2w1, a2w2,
                                              ri, rotT, wT1, wT2, wTs, auxT, invp);
  k_conv1<<<dim3(784), dim3(256), 0, stream>>>(fd1, fd2, wT1, ht0, ht1, ht2, ht3);
  k_conv2<<<dim3(364), dim3(128), 0, stream>>>(fd1, fd2, ht0, ht1, ht2, ht3, wT2,
                                               mb1, mb2, wTs, mbs, F);
  k_codes<<<dim3(79, 8), dim3(256), 0, stream>>>(F, rotT, ri, codes);
  k_sort<<<dim3(8), dim3(256), 0, stream>>>(codes, rank_of, n0);
  k_point<<<dim3(5), dim3(576), 0, stream>>>(fd1, reff, ri, auxT, a1b1, a1b2,
                                             a2b1, a2b2, F, SC);
  k_ab<<<dim3(157), dim3(256), 0, stream>>>(rank_of, n0, SC, AB);
  k_out<<<dim3(40, 2), dim3(256), 0, stream>>>(invp, AB, SC, (float*)d_out);
}

// Round 6
// 135.837 us; speedup vs baseline: 3.9116x; 1.1555x over previous
//
#include <hip/hip_runtime.h>

// Flip to 0 if absmax fails large: selects legacy (non-partitionable) JAX threefry stream.
#define JAX_THREEFRY_PARTITIONABLE 1

namespace {

constexpr int BN   = 2;      // batch
constexpr int C0   = 64;
constexpr int HH   = 100;
constexpr int WWW  = 100;
constexpr int LL   = 10000;  // H*W
constexpr int TL   = 20000;  // 2L
constexpr int CHK  = 144;
constexpr int NCHK = 139;    // (TL+16)/144
constexpr int NPAD = 16;
constexpr int WINR = 432;    // 3*144

// ws layout in float slots
constexpr int OFF_ROT  = 0;                    // rotT [4][64][16]
constexpr int OFF_WT1  = OFF_ROT + 4096;       // [64*9][16]
constexpr int OFF_WT2  = OFF_WT1 + 9216;       // [16*9][16]
constexpr int OFF_WTS  = OFF_WT2 + 2304;       // [64][16]
constexpr int OFF_HT0  = OFF_WTS + 1024;       // conv1 partial kq=0 [4][16][10000]; becomes h after k_hsum
constexpr int OFF_HT1  = OFF_HT0 + 640000;     // kq=1
constexpr int OFF_HT2  = OFF_HT1 + 640000;     // kq=2
constexpr int OFF_HT3  = OFF_HT2 + 640000;     // kq=3
constexpr int OFF_F    = OFF_HT3 + 640000;     // F [2][20000][16]
constexpr int OFF_SC   = OFF_F + 640000;       // SC [2][136]
constexpr int OFF_AB   = OFF_SC + 272;         // AB [2][20000][2]
constexpr int OFF_CODE = OFF_AB + 80000;       // codes u8 [8][20000]
constexpr int OFF_RANK = OFF_CODE + 40000;     // rank int [8][20000]
constexpr int OFF_N0   = OFF_RANK + 160000;    // n0 int [8][139]
constexpr int OFF_INV  = OFF_N0 + 1112;        // inv int [10000]
constexpr int OFF_AUX  = OFF_INV + 10000;      // auxT: 4 x [576][64]

constexpr int AUXW = 36864;  // 64*64*9

__device__ __forceinline__ unsigned rotl32(unsigned v, int r) {
  return (v << r) | (v >> (32 - r));
}

// JAX threefry2x32, 20 rounds, key injection every 4.
__device__ void tf2x32(unsigned k0, unsigned k1, unsigned x0, unsigned x1,
                       unsigned& o0, unsigned& o1) {
  unsigned ks2 = k0 ^ k1 ^ 0x1BD11BDAu;
  x0 += k0; x1 += k1;
#define TFR(r) { x0 += x1; x1 = rotl32(x1, r); x1 ^= x0; }
  TFR(13) TFR(15) TFR(26) TFR(6)  x0 += k1;  x1 += ks2 + 1u;
  TFR(17) TFR(29) TFR(16) TFR(24) x0 += ks2; x1 += k0 + 2u;
  TFR(13) TFR(15) TFR(26) TFR(6)  x0 += k0;  x1 += k1 + 3u;
  TFR(17) TFR(29) TFR(16) TFR(24) x0 += k1;  x1 += ks2 + 4u;
  TFR(13) TFR(15) TFR(26) TFR(6)  x0 += ks2; x1 += k0 + 5u;
#undef TFR
  o0 = x0; o1 = x1;
}

// XLA's ErfInv32 polynomial (math.cc), no fp contraction to match XLA rounding.
__device__ float xla_erfinv(float x) {
#pragma clang fp contract(off)
  float w = -log1pf(-x * x);
  float p;
  if (w < 5.0f) {
    w = w - 2.5f;
    p = 2.81022636e-08f;
    p = 3.43273939e-07f  + p * w;
    p = -3.5233877e-06f  + p * w;
    p = -4.39150654e-06f + p * w;
    p = 0.00021858087f   + p * w;
    p = -0.00125372503f  + p * w;
    p = -0.00417768164f  + p * w;
    p = 0.246640727f     + p * w;
    p = 1.50140941f      + p * w;
  } else {
    w = sqrtf(w) - 3.0f;
    p = -0.000200214257f;
    p = 0.000100950558f + p * w;
    p = 0.00134934322f  + p * w;
    p = -0.00367342844f + p * w;
    p = 0.00573950773f  + p * w;
    p = -0.0076224613f  + p * w;
    p = 0.00943887047f  + p * w;
    p = 1.00167406f     + p * w;
    p = 2.83297682f     + p * w;
  }
  return p * x;
}

// Merged prep: aux weight transposes + rot RNG + m-weight transposes + inv perm.
__global__ void k_prep(const float* __restrict__ mw1, const float* __restrict__ mw2,
                       const float* __restrict__ mws,
                       const float* __restrict__ a1w1, const float* __restrict__ a1w2,
                       const float* __restrict__ a2w1, const float* __restrict__ a2w2,
                       const int* __restrict__ ri,
                       float* __restrict__ rotT, float* __restrict__ wT1,
                       float* __restrict__ wT2, float* __restrict__ wTs,
                       float* __restrict__ auxT, int* __restrict__ inv) {
  int gid = blockIdx.x * 256 + threadIdx.x;
  if (gid < 4 * AUXW) {
    int wsel = gid / AUXW, j = gid % AUXW;
    const float* src = (wsel == 0) ? a1w1 : (wsel == 1) ? a1w2 : (wsel == 2) ? a2w1 : a2w2;
    int co = j / 576, r = j % 576;                 // coalesced read
    auxT[wsel * AUXW + r * 64 + co] = src[j];
    return;
  }
  int g2 = gid - 4 * AUXW;
  if (g2 < 4096) {
    int i = g2;
    unsigned o0, o1, bits;
#if JAX_THREEFRY_PARTITIONABLE
    tf2x32(0u, 42u, 0u, (unsigned)i, o0, o1);
    bits = o0 ^ o1;
#else
    if (i < 2048) { tf2x32(0u, 42u, (unsigned)i, (unsigned)(i + 2048), o0, o1); bits = o0; }
    else          { tf2x32(0u, 42u, (unsigned)(i - 2048), (unsigned)i, o0, o1); bits = o1; }
#endif
    unsigned fb = (bits >> 9) | 0x3f800000u;
    float f = __uint_as_float(fb) - 1.0f;
    const float lo = __uint_as_float(0xBF7FFFFFu);  // nextafter(-1,0)
    float u = fmaxf(lo, f * 2.0f + lo);
    float r = __uint_as_float(0x3FB504F3u) * xla_erfinv(u);  // sqrt(2)*erfinv(u)
    int c = i >> 8, h = (i >> 6) & 3, j = i & 63;
    rotT[(h * 64 + j) * 16 + c] = r;
    return;
  }
  int g3 = g2 - 4096;
  if (g3 < 9216) {
    { int o = g3 / 576; int r = g3 % 576; wT1[r * 16 + o] = mw1[g3]; }
    if (g3 < 2304) { int o = g3 / 144; int r = g3 % 144; wT2[r * 16 + o] = mw2[g3]; }
    if (g3 < 1024) { int o = g3 / 64;  int ci = g3 % 64; wTs[ci * 16 + o] = mws[g3]; }
    return;
  }
  int g4 = g3 - 9216;
  if (g4 < TL) {
    int p = ri[g4];
    if (p < LL) inv[p] = g4;
  }
}

// conv1 (m-block, 64->16 3x3), K-split in 4 quarters of 16 ci.
// block = (img n, kq, 16x16 tile); thread = (co, y-row) over 16-px x-strip.
// 4-ci weight chunks register-stationary; partial sums (no bias/relu) to ht[kq].
__global__ __launch_bounds__(256) void k_conv1(
    const float* __restrict__ fd1, const float* __restrict__ fd2,
    const float* __restrict__ wT1,
    float* __restrict__ ht0, float* __restrict__ ht1,
    float* __restrict__ ht2, float* __restrict__ ht3) {
  int blk = blockIdx.x;
  int kq = blk & 3;
  int rest = blk >> 2;
  int n = rest / 49, tile = rest % 49;
  int ty0 = (tile / 7) * 16, tx0 = (tile % 7) * 16;
  const float* in = ((n >> 1) ? fd2 : fd1) + (n & 1) * (C0 * LL) + (kq * 16) * LL;
  float* htk = ((kq == 0) ? ht0 : (kq == 1) ? ht1 : (kq == 2) ? ht2 : ht3) + n * 16 * LL;
  int tid = threadIdx.x;
  int co = tid & 15, yl = tid >> 4;

  __shared__ float sIn[16 * 18 * 20];   // [ci][18 rows][20 pad] halo tile (23KB)
  __shared__ float sW[144 * 16];        // this quarter's weights [(ci*9+t)][co] (9.2KB)

  for (int i = tid; i < 144 * 16; i += 256) sW[i] = wT1[kq * 2304 + i];
  for (int idx = tid; idx < 16 * 18 * 18; idx += 256) {
    int ci = idx / 324, r = idx % 324, iy = r / 18, ix = r % 18;
    int gy = ty0 - 1 + iy, gx = tx0 - 1 + ix;
    float v = 0.f;
    if (gy >= 0 && gy < HH && gx >= 0 && gx < WWW) v = in[ci * LL + gy * WWW + gx];
    sIn[ci * 360 + iy * 20 + ix] = v;
  }
  __syncthreads();

  float acc[16];
#pragma unroll
  for (int p = 0; p < 16; ++p) acc[p] = 0.f;

  for (int cc = 0; cc < 4; ++cc) {   // 4-ci chunks (keeps VGPR <= ~128)
    float w[4][9];
#pragma unroll
    for (int c4 = 0; c4 < 4; ++c4)
#pragma unroll
      for (int t = 0; t < 9; ++t)
        w[c4][t] = sW[((cc * 4 + c4) * 9 + t) * 16 + co];
#pragma unroll
    for (int c4 = 0; c4 < 4; ++c4) {
      const float* rowb = &sIn[(cc * 4 + c4) * 360 + yl * 20];
#pragma unroll
      for (int dy = 0; dy < 3; ++dy) {
        const float* r = rowb + dy * 20;
        float v[18];
#pragma unroll
        for (int k = 0; k < 18; ++k) v[k] = r[k];
#pragma unroll
        for (int dx = 0; dx < 3; ++dx) {
          float wv = w[c4][dy * 3 + dx];
#pragma unroll
          for (int p = 0; p < 16; ++p) acc[p] = fmaf(v[p + dx], wv, acc[p]);
        }
      }
    }
  }

  int yv = ty0 + yl;
  if (yv < HH) {
    float* op = htk + co * LL + yv * WWW;
#pragma unroll
    for (int g = 0; g < 4; ++g) {
      int xg = tx0 + g * 4;
      if (xg < WWW) {
        float4 s = make_float4(acc[g * 4], acc[g * 4 + 1], acc[g * 4 + 2], acc[g * 4 + 3]);
        *(float4*)&op[xg] = s;
      }
    }
  }
}

// h = relu(ht0+ht1+ht2+ht3+mb1), written in-place to ht0. float4 over 2.56M floats.
__global__ __launch_bounds__(256) void k_hsum(
    const float* __restrict__ ht1, const float* __restrict__ ht2,
    const float* __restrict__ ht3, const float* __restrict__ mb1,
    float* __restrict__ ht0) {
  int i4 = blockIdx.x * 256 + threadIdx.x;
  if (i4 >= 160000) return;
  int base = i4 * 4;
  int ch = (base / 10000) & 15;    // [n][ch][10000]; 10000 % 4 == 0 so no crossing
  float bb = mb1[ch];
  float4 a = *(const float4*)&ht0[base];
  float4 c = *(const float4*)&ht1[base];
  float4 d = *(const float4*)&ht2[base];
  float4 e = *(const float4*)&ht3[base];
  float4 r;
  r.x = fmaxf(a.x + c.x + d.x + e.x + bb, 0.f);
  r.y = fmaxf(a.y + c.y + d.y + e.y + bb, 0.f);
  r.z = fmaxf(a.z + c.z + d.z + e.z + bb, 0.f);
  r.w = fmaxf(a.w + c.w + d.w + e.w + bb, 0.f);
  *(float4*)&ht0[base] = r;
}

// conv2 (16->16 3x3 + b2) + skip (1x1 64->16 + mbs) on precomputed h (=ht0).
// block = (img n, 8y x 16x tile); 512 threads = (co, xq, yl); 4 px per thread.
__global__ __launch_bounds__(512) void k_conv2(
    const float* __restrict__ fd1, const float* __restrict__ fd2,
    const float* __restrict__ h,
    const float* __restrict__ wT2, const float* __restrict__ mb2,
    const float* __restrict__ wTs, const float* __restrict__ mbs,
    float* __restrict__ F) {
  int blk = blockIdx.x;
  int n = blk / 91, tile = blk % 91;
  int yt = tile / 7, xt = tile % 7;       // 13 y-tiles x 7 x-tiles
  int ty0 = yt * 8, tx0 = xt * 16;
  int src = n >> 1, b = n & 1;
  const float* in = (src ? fd2 : fd1) + b * (C0 * LL);
  const float* hb = h + n * 16 * LL;
  int tid = threadIdx.x;
  int co = tid & 15, xq = (tid >> 4) & 3, yl = tid >> 6;   // yl 0..7

  __shared__ float sW2[144 * 16];         // [(ci*9+t)][co]
  __shared__ float sWs[64 * 16];          // [ci][co]
  __shared__ float sH[16 * 10 * 20];      // h halo [ci][10 rows][20 pad (18 used)]
  __shared__ float sSkip[16 * 8 * 17];    // skip chunk [ci16][8][17 pad (16 used)]

  for (int i = tid; i < 144 * 16; i += 512) sW2[i] = wT2[i];
  for (int i = tid; i < 64 * 16; i += 512) sWs[i] = wTs[i];
  for (int idx = tid; idx < 16 * 10 * 18; idx += 512) {
    int ci = idx / 180, r = idx % 180, iy = r / 18, ix = r % 18;
    int gy = ty0 - 1 + iy, gx = tx0 - 1 + ix;
    float v = 0.f;
    if (gy >= 0 && gy < HH && gx >= 0 && gx < WWW) v = hb[ci * LL + gy * WWW + gx];
    sH[ci * 200 + iy * 20 + ix] = v;
  }
  __syncthreads();

  float acc[4];
  float bias = mb2[co] + mbs[co];
#pragma unroll
  for (int p = 0; p < 4; ++p) acc[p] = bias;

  // conv 3x3 over the 16 h-channels
  for (int ci = 0; ci < 16; ++ci) {
    const float* rowb = &sH[ci * 200 + yl * 20 + xq * 4];
#pragma unroll
    for (int dy = 0; dy < 3; ++dy) {
      const float* r = rowb + dy * 20;
      float v[6];
#pragma unroll
      for (int k = 0; k < 6; ++k) v[k] = r[k];
#pragma unroll
      for (int dx = 0; dx < 3; ++dx) {
        float wv = sW2[(ci * 9 + dy * 3 + dx) * 16 + co];
#pragma unroll
        for (int p = 0; p < 4; ++p) acc[p] = fmaf(v[p + dx], wv, acc[p]);
      }
    }
  }

  // skip 1x1 over 64 ci, staged in 4 chunks of 16 ci
  for (int cc = 0; cc < 4; ++cc) {
    __syncthreads();
    for (int idx = tid; idx < 16 * 8 * 16; idx += 512) {
      int ci = idx >> 7, r = idx & 127, iy = r >> 4, ix = r & 15;
      int gy = ty0 + iy, gx = tx0 + ix;
      float v = 0.f;
      if (gy < HH && gx < WWW) v = in[(cc * 16 + ci) * LL + gy * WWW + gx];
      sSkip[(ci * 8 + iy) * 17 + ix] = v;
    }
    __syncthreads();
    for (int c16 = 0; c16 < 16; ++c16) {
      float wv = sWs[(cc * 16 + c16) * 16 + co];
      const float* sv = &sSkip[(c16 * 8 + yl) * 17 + xq * 4];
#pragma unroll
      for (int p = 0; p < 4; ++p) acc[p] = fmaf(sv[p], wv, acc[p]);
    }
  }

  int yv = ty0 + yl;
  if (yv < HH) {
    float* Fb = F + (b * TL + src * LL + yv * WWW) * 16 + co;
#pragma unroll
    for (int p = 0; p < 4; ++p) {
      int xv = tx0 + xq * 4 + p;
      if (xv < WWW) Fb[xv * 16] = acc[p];
    }
  }
}

// codes in permuted order: code[bh][t'] = argmax over [rv, -rv] at row ri[t']
__global__ __launch_bounds__(256) void k_codes(
    const float* __restrict__ F, const float* __restrict__ rotT,
    const int* __restrict__ ri, unsigned char* __restrict__ codes) {
  int bh = blockIdx.y;
  int b = bh >> 2, h = bh & 3;
  __shared__ float srot[1024];
  int tid = threadIdx.x;
  for (int i = tid; i < 1024; i += 256) srot[i] = rotT[h * 1024 + i];
  __syncthreads();
  int t = blockIdx.x * 256 + tid;
  if (t >= TL) return;
  int pos = ri[t];
  const float* Fr = F + (b * TL + pos) * 16;
  float q[16];
#pragma unroll
  for (int c = 0; c < 16; ++c) q[c] = Fr[c];
  float best = -1e30f; int bi = 0;
  float worst = 1e30f; int wi = 0;
  for (int j = 0; j < 64; ++j) {
    float v = 0.f;
    const float* rp = srot + j * 16;
#pragma unroll
    for (int c = 0; c < 16; ++c) v = fmaf(q[c], rp[c], v);
    if (v > best)  { best = v;  bi = j; }
    if (v < worst) { worst = v; wi = j; }
  }
  int code = (best >= -worst) ? bi : (64 + wi);
  codes[bh * TL + t] = (unsigned char)code;
}

// stable counting sort per (b,h); emit rank_of[t'] and even-parity chunk counts n0
__global__ __launch_bounds__(256) void k_sort(
    const unsigned char* __restrict__ codes,
    int* __restrict__ rank_of, int* __restrict__ n0g) {
  int bh = blockIdx.x;
  const unsigned char* keys = codes + bh * TL;
  __shared__ unsigned short cnt[240][128];
  __shared__ unsigned int totals[128];
  __shared__ unsigned int baseoff[128];
  __shared__ unsigned int n0s[NCHK];
  int tid = threadIdx.x;
  for (int i = tid; i < 240 * 128 / 2; i += 256) ((unsigned int*)cnt)[i] = 0u;
  for (int i = tid; i < NCHK; i += 256) n0s[i] = 0u;
  __syncthreads();
  const int SEG = 84;
  int base = tid * SEG;
  int nloc = (tid < 240) ? (TL - base) : 0;
  if (nloc > SEG) nloc = SEG;
  if (nloc < 0) nloc = 0;
  for (int e = 0; e < nloc; ++e) cnt[tid][keys[base + e]]++;
  __syncthreads();
  if (tid < 128) {
    unsigned int s = 0;
    for (int g = 0; g < 240; ++g) s += cnt[g][tid];
    totals[tid] = s;
  }
  __syncthreads();
  if (tid == 0) {
    unsigned int run = 0;
    for (int c = 0; c < 128; ++c) { baseoff[c] = run; run += totals[c]; }
  }
  __syncthreads();
  if (tid < 128) {
    unsigned int run = baseoff[tid];
    for (int g = 0; g < 240; ++g) {
      unsigned int v = cnt[g][tid];
      cnt[g][tid] = (unsigned short)run;
      run += v;
    }
  }
  __syncthreads();
  for (int e = 0; e < nloc; ++e) {
    int idx = base + e;
    int c = keys[idx];
    int r = cnt[tid][c]++;
    rank_of[bh * TL + idx] = r;
    if (!(idx & 1)) {
      atomicAdd(&n0s[r / CHK], 1u);
      if (r >= TL - NPAD) atomicAdd(&n0s[NCHK - 1], 1u);
    }
  }
  __syncthreads();
  for (int i = tid; i < NCHK; i += 256) n0g[bh * NCHK + i] = (int)n0s[i];
}

// blocks 0..3: rA/rB point-resblock, LDS-staged; block 4: per-batch E scalars.
__global__ __launch_bounds__(576) void k_point(
    const float* __restrict__ fd1, const float* __restrict__ refin,
    const int* __restrict__ ri, const float* __restrict__ auxT,
    const float* __restrict__ a1b1, const float* __restrict__ a1b2,
    const float* __restrict__ a2b1, const float* __restrict__ a2b2,
    const float* __restrict__ F, float* __restrict__ SC) {
  int tid = threadIdx.x;
  if (blockIdx.x == 4) {
#pragma clang fp contract(off)
    int b = tid;
    if (b >= BN) return;
    int j0 = ri[0], jL = ri[LL];
    const float* qA = F + (b * TL + j0) * 16;
    const float* qB = F + (b * TL + jL) * 16;
    float nA = 0.f, nB = 0.f;
    for (int c = 0; c < 16; ++c) { nA += qA[c] * qA[c]; nB += qB[c] * qB[c]; }
    float mA = fmaxf(sqrtf(nA), 5e-5f), mB = fmaxf(sqrtf(nB), 5e-5f);
    float d00 = 0.f, d01 = 0.f, d10 = 0.f, d11 = 0.f;
    for (int c = 0; c < 16; ++c) {
      float kAc = qA[c] / mA, kBc = qB[c] / mB;
      d00 += qA[c] * kAc; d01 += qA[c] * kBc;
      d10 += qB[c] * kAc; d11 += qB[c] * kBc;
    }
    float zA = (j0 < LL) ? 0.01f : 0.99f;
    float zB = (jL < LL) ? 0.01f : 0.99f;
    float* sc = SC + b * 136;
    sc[0] = expf(d00) * zA; sc[1] = expf(d01) * zB;
    sc[2] = expf(d10) * zA; sc[3] = expf(d11) * zB;
    return;
  }
  int b = blockIdx.x & 1, which = blockIdx.x >> 1;
  int pos = ri[which * LL];
  const float *in, *w1T, *b1, *w2T, *b2;
  int sp;
  if (pos < LL) {
    in = fd1 + b * C0 * LL; w1T = auxT; b1 = a1b1; w2T = auxT + AUXW; b2 = a1b2; sp = pos;
  } else {
    in = refin + b * C0 * LL; w1T = auxT + 2 * AUXW; b1 = a2b1; w2T = auxT + 3 * AUXW;
    b2 = a2b2; sp = pos - LL;
  }
  int y = sp / WWW, x = sp % WWW;

  __shared__ float sPatch[64][25];
  __shared__ float sW[144 * 64];
  __shared__ float sH[9][64];
  __shared__ float sPart[9][64];

  for (int idx = tid; idx < 64 * 25; idx += 576) {
    int ci = idx / 25, pp = idx % 25;
    int gy = y - 2 + pp / 5, gx = x - 2 + pp % 5;
    float v = 0.f;
    if (gy >= 0 && gy < HH && gx >= 0 && gx < WWW) v = in[ci * LL + gy * WWW + gx];
    sPatch[ci][pp] = v;
  }

  int p = tid / 64, ch = tid & 63;
  int p3 = p / 3, pm = p % 3;
  int yy = y + p3 - 1, xx = x + pm - 1;
  bool inb = (yy >= 0) && (yy < HH) && (xx >= 0) && (xx < WWW);

  float acc0 = 0.f, acc1 = 0.f;
  for (int cc = 0; cc < 4; ++cc) {
    __syncthreads();
    for (int i = tid; i < 144 * 64; i += 576) sW[i] = w1T[cc * 9216 + i];
    __syncthreads();
    if (inb) {
#pragma unroll
      for (int ci = 0; ci < 16; ++ci) {
        const float* wp = &sW[ci * 9 * 64 + ch];
        const float* pr = &sPatch[cc * 16 + ci][0];
#pragma unroll
        for (int t = 0; t < 9; ++t) {
          float v = pr[(p3 + t / 3) * 5 + (pm + t % 3)];
          if (ci & 1) acc1 = fmaf(v, wp[t * 64], acc1);
          else        acc0 = fmaf(v, wp[t * 64], acc0);
        }
      }
    }
  }
  sH[p][ch] = inb ? fmaxf(acc0 + acc1 + b1[ch], 0.f) : 0.f;
  __syncthreads();

  {
    float part = 0.f;
    const float* wbase = w2T + p * 64 + ch;
    for (int ci = 0; ci < 64; ++ci) part = fmaf(sH[p][ci], wbase[ci * 9 * 64], part);
    sPart[p][ch] = part;
  }
  __syncthreads();
  if (tid < 64) {
    int co = tid;
    float a = in[co * LL + y * WWW + x] + b2[co];
#pragma unroll
    for (int g = 0; g < 9; ++g) a += sPart[g][co];
    SC[b * 136 + 4 + which * 64 + co] = a;
  }
}

// per (b, t'): alpha/beta = hash-summed numerators over hash-summed denominators
__global__ void k_ab(const int* __restrict__ rank_of, const int* __restrict__ n0,
                     const float* __restrict__ SC, float* __restrict__ AB) {
  int gid = blockIdx.x * 256 + threadIdx.x;
  if (gid >= BN * TL) return;
  int b = gid / TL, t = gid % TL;
  int si = t & 1;
  float e0 = SC[b * 136 + si * 2 + 0];
  float e1 = SC[b * 136 + si * 2 + 1];
  float s0 = 0.f, s1 = 0.f;
  for (int h = 0; h < 4; ++h) {
    int r = rank_of[(b * 4 + h) * TL + t];
    int k = r / CHK;
    int km = (k == 0) ? NCHK - 1 : k - 1;
    int kp = (k == NCHK - 1) ? 0 : k + 1;
    const int* nb = n0 + (b * 4 + h) * NCHK;
    int W0 = nb[k] + nb[km] + nb[kp];
    s0 += (float)W0 * e0;
    s1 += (float)(WINR - W0) * e1;
  }
  float invd = 1.f / (s0 + s1);
  AB[(b * TL + t) * 2 + 0] = s0 * invd;
  AB[(b * TL + t) * 2 + 1] = s1 * invd;
}

// out[b][c][p] = alpha*rA[c] + beta*rB[c], p < L
__global__ __launch_bounds__(256) void k_out(
    const int* __restrict__ inv, const float* __restrict__ AB,
    const float* __restrict__ SC, float* __restrict__ out) {
  int b = blockIdx.y;
  int p = blockIdx.x * 256 + threadIdx.x;
  if (p >= LL) return;
  int t = inv[p];
  float al = AB[(b * TL + t) * 2 + 0];
  float be = AB[(b * TL + t) * 2 + 1];
  const float* rA = SC + b * 136 + 4;
  const float* rB = rA + 64;
  float* o = out + b * C0 * LL + p;
#pragma unroll
  for (int c = 0; c < 64; ++c) o[c * LL] = al * rA[c] + be * rB[c];
}

}  // namespace

extern "C" void kernel_launch(void* const* d_in, const int* in_sizes, int n_in,
                              void* d_out, int out_size, void* d_ws, size_t ws_size,
                              hipStream_t stream) {
  const float* fd1  = (const float*)d_in[0];
  const float* fd2  = (const float*)d_in[1];
  const float* reff = (const float*)d_in[2];
  const int*   ri   = (const int*)d_in[3];
  const float* mw1  = (const float*)d_in[4];
  const float* mb1  = (const float*)d_in[5];
  const float* mw2  = (const float*)d_in[6];
  const float* mb2  = (const float*)d_in[7];
  const float* mws  = (const float*)d_in[8];
  const float* mbs  = (const float*)d_in[9];
  const float* a1w1 = (const float*)d_in[10];
  const float* a1b1 = (const float*)d_in[11];
  const float* a1w2 = (const float*)d_in[12];
  const float* a1b2 = (const float*)d_in[13];
  const float* a2w1 = (const float*)d_in[14];
  const float* a2b1 = (const float*)d_in[15];
  const float* a2w2 = (const float*)d_in[16];
  const float* a2b2 = (const float*)d_in[17];

  float* ws = (float*)d_ws;
  float* rotT = ws + OFF_ROT;
  float* wT1  = ws + OFF_WT1;
  float* wT2  = ws + OFF_WT2;
  float* wTs  = ws + OFF_WTS;
  float* ht0  = ws + OFF_HT0;
  float* ht1  = ws + OFF_HT1;
  float* ht2  = ws + OFF_HT2;
  float* ht3  = ws + OFF_HT3;
  float* F    = ws + OFF_F;
  float* SC   = ws + OFF_SC;
  float* AB   = ws + OFF_AB;
  unsigned char* codes = (unsigned char*)(ws + OFF_CODE);
  int* rank_of = (int*)(ws + OFF_RANK);
  int* n0      = (int*)(ws + OFF_N0);
  int* invp    = (int*)(ws + OFF_INV);
  float* auxT  = ws + OFF_AUX;

  k_prep<<<dim3(707), dim3(256), 0, stream>>>(mw1, mw2, mws, a1w1, a1w2, a2w1, a2w2,
                                              ri, rotT, wT1, wT2, wTs, auxT, invp);
  k_conv1<<<dim3(784), dim3(256), 0, stream>>>(fd1, fd2, wT1, ht0, ht1, ht2, ht3);
  k_hsum<<<dim3(625), dim3(256), 0, stream>>>(ht1, ht2, ht3, mb1, ht0);
  k_conv2<<<dim3(364), dim3(512), 0, stream>>>(fd1, fd2, ht0, wT2, mb2, wTs, mbs, F);
  k_codes<<<dim3(79, 8), dim3(256), 0, stream>>>(F, rotT, ri, codes);
  k_sort<<<dim3(8), dim3(256), 0, stream>>>(codes, rank_of, n0);
  k_point<<<dim3(5), dim3(576), 0, stream>>>(fd1, reff, ri, auxT, a1b1, a1b2,
                                             a2b1, a2b2, F, SC);
  k_ab<<<dim3(157), dim3(256), 0, stream>>>(rank_of, n0, SC, AB);
  k_out<<<dim3(40, 2), dim3(256), 0, stream>>>(invp, AB, SC, (float*)d_out);
}

// Round 7
// 132.767 us; speedup vs baseline: 4.0021x; 1.0231x over previous
//
#include <hip/hip_runtime.h>

// Flip to 0 if absmax fails large: selects legacy (non-partitionable) JAX threefry stream.
#define JAX_THREEFRY_PARTITIONABLE 1

namespace {

constexpr int BN   = 2;      // batch
constexpr int C0   = 64;
constexpr int HH   = 100;
constexpr int WWW  = 100;
constexpr int LL   = 10000;  // H*W
constexpr int TL   = 20000;  // 2L
constexpr int CHK  = 144;
constexpr int NCHK = 139;    // (TL+16)/144
constexpr int NPAD = 16;
constexpr int WINR = 432;    // 3*144

// ws layout in float slots
constexpr int OFF_ROT  = 0;                    // rotT [4][64][16]
constexpr int OFF_WT1  = OFF_ROT + 4096;       // [64*9][16]
constexpr int OFF_WT2  = OFF_WT1 + 9216;       // [16*9][16]
constexpr int OFF_WTS  = OFF_WT2 + 2304;       // [64][16]
constexpr int OFF_HT0  = OFF_WTS + 1024;       // conv1 partial kq=0 [4][16][10000]
constexpr int OFF_HT1  = OFF_HT0 + 640000;     // kq=1
constexpr int OFF_HT2  = OFF_HT1 + 640000;     // kq=2
constexpr int OFF_HT3  = OFF_HT2 + 640000;     // kq=3
constexpr int OFF_F    = OFF_HT3 + 640000;     // F [2][20000][16]
constexpr int OFF_SC   = OFF_F + 640000;       // SC [2][136]
constexpr int OFF_CODE = OFF_SC + 272;         // codes u8 [8][20000]
constexpr int OFF_RANK = OFF_CODE + 40000;     // rank int [8][20000]
constexpr int OFF_N0   = OFF_RANK + 160000;    // n0 int [8][139]
constexpr int OFF_INV  = OFF_N0 + 1112;        // inv int [10000]
constexpr int OFF_AUX  = OFF_INV + 10000;      // auxT: 4 x [576][64]

constexpr int AUXW = 36864;  // 64*64*9

__device__ __forceinline__ unsigned rotl32(unsigned v, int r) {
  return (v << r) | (v >> (32 - r));
}

// JAX threefry2x32, 20 rounds, key injection every 4.
__device__ void tf2x32(unsigned k0, unsigned k1, unsigned x0, unsigned x1,
                       unsigned& o0, unsigned& o1) {
  unsigned ks2 = k0 ^ k1 ^ 0x1BD11BDAu;
  x0 += k0; x1 += k1;
#define TFR(r) { x0 += x1; x1 = rotl32(x1, r); x1 ^= x0; }
  TFR(13) TFR(15) TFR(26) TFR(6)  x0 += k1;  x1 += ks2 + 1u;
  TFR(17) TFR(29) TFR(16) TFR(24) x0 += ks2; x1 += k0 + 2u;
  TFR(13) TFR(15) TFR(26) TFR(6)  x0 += k0;  x1 += k1 + 3u;
  TFR(17) TFR(29) TFR(16) TFR(24) x0 += k1;  x1 += ks2 + 4u;
  TFR(13) TFR(15) TFR(26) TFR(6)  x0 += ks2; x1 += k0 + 5u;
#undef TFR
  o0 = x0; o1 = x1;
}

// XLA's ErfInv32 polynomial (math.cc), no fp contraction to match XLA rounding.
__device__ float xla_erfinv(float x) {
#pragma clang fp contract(off)
  float w = -log1pf(-x * x);
  float p;
  if (w < 5.0f) {
    w = w - 2.5f;
    p = 2.81022636e-08f;
    p = 3.43273939e-07f  + p * w;
    p = -3.5233877e-06f  + p * w;
    p = -4.39150654e-06f + p * w;
    p = 0.00021858087f   + p * w;
    p = -0.00125372503f  + p * w;
    p = -0.00417768164f  + p * w;
    p = 0.246640727f     + p * w;
    p = 1.50140941f      + p * w;
  } else {
    w = sqrtf(w) - 3.0f;
    p = -0.000200214257f;
    p = 0.000100950558f + p * w;
    p = 0.00134934322f  + p * w;
    p = -0.00367342844f + p * w;
    p = 0.00573950773f  + p * w;
    p = -0.0076224613f  + p * w;
    p = 0.00943887047f  + p * w;
    p = 1.00167406f     + p * w;
    p = 2.83297682f     + p * w;
  }
  return p * x;
}

// Merged prep: aux weight transposes + rot RNG + m-weight transposes + inv perm.
__global__ void k_prep(const float* __restrict__ mw1, const float* __restrict__ mw2,
                       const float* __restrict__ mws,
                       const float* __restrict__ a1w1, const float* __restrict__ a1w2,
                       const float* __restrict__ a2w1, const float* __restrict__ a2w2,
                       const int* __restrict__ ri,
                       float* __restrict__ rotT, float* __restrict__ wT1,
                       float* __restrict__ wT2, float* __restrict__ wTs,
                       float* __restrict__ auxT, int* __restrict__ inv) {
  int gid = blockIdx.x * 256 + threadIdx.x;
  if (gid < 4 * AUXW) {
    int wsel = gid / AUXW, j = gid % AUXW;
    const float* src = (wsel == 0) ? a1w1 : (wsel == 1) ? a1w2 : (wsel == 2) ? a2w1 : a2w2;
    int co = j / 576, r = j % 576;                 // coalesced read
    auxT[wsel * AUXW + r * 64 + co] = src[j];
    return;
  }
  int g2 = gid - 4 * AUXW;
  if (g2 < 4096) {
    int i = g2;
    unsigned o0, o1, bits;
#if JAX_THREEFRY_PARTITIONABLE
    tf2x32(0u, 42u, 0u, (unsigned)i, o0, o1);
    bits = o0 ^ o1;
#else
    if (i < 2048) { tf2x32(0u, 42u, (unsigned)i, (unsigned)(i + 2048), o0, o1); bits = o0; }
    else          { tf2x32(0u, 42u, (unsigned)(i - 2048), (unsigned)i, o0, o1); bits = o1; }
#endif
    unsigned fb = (bits >> 9) | 0x3f800000u;
    float f = __uint_as_float(fb) - 1.0f;
    const float lo = __uint_as_float(0xBF7FFFFFu);  // nextafter(-1,0)
    float u = fmaxf(lo, f * 2.0f + lo);
    float r = __uint_as_float(0x3FB504F3u) * xla_erfinv(u);  // sqrt(2)*erfinv(u)
    int c = i >> 8, h = (i >> 6) & 3, j = i & 63;
    rotT[(h * 64 + j) * 16 + c] = r;
    return;
  }
  int g3 = g2 - 4096;
  if (g3 < 9216) {
    { int o = g3 / 576; int r = g3 % 576; wT1[r * 16 + o] = mw1[g3]; }
    if (g3 < 2304) { int o = g3 / 144; int r = g3 % 144; wT2[r * 16 + o] = mw2[g3]; }
    if (g3 < 1024) { int o = g3 / 64;  int ci = g3 % 64; wTs[ci * 16 + o] = mws[g3]; }
    return;
  }
  int g4 = g3 - 9216;
  if (g4 < TL) {
    int p = ri[g4];
    if (p < LL) inv[p] = g4;
  }
}

// conv1 (m-block, 64->16 3x3), K-split in 4 quarters of 16 ci.
// XCD-swizzled blocks: the 4 kq-siblings of a tile land on the same XCD L2.
// thread = (co, y-row) over 16-px x-strip; 4-ci weight chunks register-stationary.
__global__ __launch_bounds__(256) void k_conv1(
    const float* __restrict__ fd1, const float* __restrict__ fd2,
    const float* __restrict__ wT1,
    float* __restrict__ ht0, float* __restrict__ ht1,
    float* __restrict__ ht2, float* __restrict__ ht3) {
  // grid = 784 = 8*98 exactly; default dispatch is round-robin over 8 XCDs, so
  // fixing (blk % 8) per contiguous orig-range keeps neighbors on one XCD.
  int x = blockIdx.x;
  int blk = (x & 7) * 98 + (x >> 3);
  int kq = blk & 3;
  int rest = blk >> 2;
  int n = rest / 49, tile = rest % 49;
  int ty0 = (tile / 7) * 16, tx0 = (tile % 7) * 16;
  const float* in = ((n >> 1) ? fd2 : fd1) + (n & 1) * (C0 * LL) + (kq * 16) * LL;
  float* htk = ((kq == 0) ? ht0 : (kq == 1) ? ht1 : (kq == 2) ? ht2 : ht3) + n * 16 * LL;
  int tid = threadIdx.x;
  int co = tid & 15, yl = tid >> 4;

  __shared__ float sIn[16 * 18 * 20];   // [ci][18 rows][20 pad] halo tile (23KB)
  __shared__ float sW[144 * 16];        // this quarter's weights [(ci*9+t)][co] (9.2KB)

  for (int i = tid; i < 144 * 16; i += 256) sW[i] = wT1[kq * 2304 + i];
  for (int idx = tid; idx < 16 * 18 * 18; idx += 256) {
    int ci = idx / 324, r = idx % 324, iy = r / 18, ix = r % 18;
    int gy = ty0 - 1 + iy, gx = tx0 - 1 + ix;
    float v = 0.f;
    if (gy >= 0 && gy < HH && gx >= 0 && gx < WWW) v = in[ci * LL + gy * WWW + gx];
    sIn[ci * 360 + iy * 20 + ix] = v;
  }
  __syncthreads();

  float acc[16];
#pragma unroll
  for (int p = 0; p < 16; ++p) acc[p] = 0.f;

  for (int cc = 0; cc < 4; ++cc) {   // 4-ci chunks (keeps VGPR <= ~128)
    float w[4][9];
#pragma unroll
    for (int c4 = 0; c4 < 4; ++c4)
#pragma unroll
      for (int t = 0; t < 9; ++t)
        w[c4][t] = sW[((cc * 4 + c4) * 9 + t) * 16 + co];
#pragma unroll
    for (int c4 = 0; c4 < 4; ++c4) {
      const float* rowb = &sIn[(cc * 4 + c4) * 360 + yl * 20];
#pragma unroll
      for (int dy = 0; dy < 3; ++dy) {
        const float* r = rowb + dy * 20;
        float v[18];
#pragma unroll
        for (int k = 0; k < 18; ++k) v[k] = r[k];
#pragma unroll
        for (int dx = 0; dx < 3; ++dx) {
          float wv = w[c4][dy * 3 + dx];
#pragma unroll
          for (int p = 0; p < 16; ++p) acc[p] = fmaf(v[p + dx], wv, acc[p]);
        }
      }
    }
  }

  int yv = ty0 + yl;
  if (yv < HH) {
    float* op = htk + co * LL + yv * WWW;
#pragma unroll
    for (int g = 0; g < 4; ++g) {
      int xg = tx0 + g * 4;
      if (xg < WWW) {
        float4 s = make_float4(acc[g * 4], acc[g * 4 + 1], acc[g * 4 + 2], acc[g * 4 + 3]);
        *(float4*)&op[xg] = s;
      }
    }
  }
}

// conv2 (16->16 3x3 + b2) + skip (1x1 64->16 + mbs), with h = relu(sum ht + mb1)
// fused into the halo staging (no separate hsum pass / buffer round-trip).
// block = (img n, 8y x 16x tile); 512 threads = (co, xq, yl); 4 px per thread.
__global__ __launch_bounds__(512) void k_conv2(
    const float* __restrict__ fd1, const float* __restrict__ fd2,
    const float* __restrict__ ht0, const float* __restrict__ ht1,
    const float* __restrict__ ht2, const float* __restrict__ ht3,
    const float* __restrict__ wT2, const float* __restrict__ mb1,
    const float* __restrict__ mb2, const float* __restrict__ wTs,
    const float* __restrict__ mbs, float* __restrict__ F) {
  // XCD swizzle for 364 blocks: bijective 46/45 chunking (364 = 4*46 + 4*45).
  int xx = blockIdx.x;
  int xcd = xx & 7, slot = xx >> 3;
  int blk = (xcd < 4) ? (xcd * 46 + slot) : (184 + (xcd - 4) * 45 + slot);
  int n = blk / 91, tile = blk % 91;
  int yt = tile / 7, xt = tile % 7;       // 13 y-tiles x 7 x-tiles
  int ty0 = yt * 8, tx0 = xt * 16;
  int src = n >> 1, b = n & 1;
  const float* in = (src ? fd2 : fd1) + b * (C0 * LL);
  const float* h0 = ht0 + n * 16 * LL;
  const float* h1 = ht1 + n * 16 * LL;
  const float* h2 = ht2 + n * 16 * LL;
  const float* h3 = ht3 + n * 16 * LL;
  int tid = threadIdx.x;
  int co = tid & 15, xq = (tid >> 4) & 3, yl = tid >> 6;   // yl 0..7

  __shared__ float sW2[144 * 16];         // [(ci*9+t)][co]
  __shared__ float sWs[64 * 16];          // [ci][co]
  __shared__ float sH[16 * 10 * 20];      // h halo [ci][10 rows][20 pad (18 used)]
  __shared__ float sSkip[16 * 8 * 17];    // skip chunk [ci16][8][17 pad (16 used)]

  for (int i = tid; i < 144 * 16; i += 512) sW2[i] = wT2[i];
  for (int i = tid; i < 64 * 16; i += 512) sWs[i] = wTs[i];
  for (int idx = tid; idx < 16 * 10 * 18; idx += 512) {
    int ci = idx / 180, r = idx % 180, iy = r / 18, ix = r % 18;
    int gy = ty0 - 1 + iy, gx = tx0 - 1 + ix;
    float v = 0.f;
    if (gy >= 0 && gy < HH && gx >= 0 && gx < WWW) {
      int o = ci * LL + gy * WWW + gx;
      v = fmaxf(h0[o] + h1[o] + h2[o] + h3[o] + mb1[ci], 0.f);
    }
    sH[ci * 200 + iy * 20 + ix] = v;
  }
  __syncthreads();

  float acc[4];
  float bias = mb2[co] + mbs[co];
#pragma unroll
  for (int p = 0; p < 4; ++p) acc[p] = bias;

  // conv 3x3 over the 16 h-channels
  for (int ci = 0; ci < 16; ++ci) {
    const float* rowb = &sH[ci * 200 + yl * 20 + xq * 4];
#pragma unroll
    for (int dy = 0; dy < 3; ++dy) {
      const float* r = rowb + dy * 20;
      float v[6];
#pragma unroll
      for (int k = 0; k < 6; ++k) v[k] = r[k];
#pragma unroll
      for (int dx = 0; dx < 3; ++dx) {
        float wv = sW2[(ci * 9 + dy * 3 + dx) * 16 + co];
#pragma unroll
        for (int p = 0; p < 4; ++p) acc[p] = fmaf(v[p + dx], wv, acc[p]);
      }
    }
  }

  // skip 1x1 over 64 ci, staged in 4 chunks of 16 ci
  for (int cc = 0; cc < 4; ++cc) {
    __syncthreads();
    for (int idx = tid; idx < 16 * 8 * 16; idx += 512) {
      int ci = idx >> 7, r = idx & 127, iy = r >> 4, ix = r & 15;
      int gy = ty0 + iy, gx = tx0 + ix;
      float v = 0.f;
      if (gy < HH && gx < WWW) v = in[(cc * 16 + ci) * LL + gy * WWW + gx];
      sSkip[(ci * 8 + iy) * 17 + ix] = v;
    }
    __syncthreads();
    for (int c16 = 0; c16 < 16; ++c16) {
      float wv = sWs[(cc * 16 + c16) * 16 + co];
      const float* sv = &sSkip[(c16 * 8 + yl) * 17 + xq * 4];
#pragma unroll
      for (int p = 0; p < 4; ++p) acc[p] = fmaf(sv[p], wv, acc[p]);
    }
  }

  int yv = ty0 + yl;
  if (yv < HH) {
    float* Fb = F + (b * TL + src * LL + yv * WWW) * 16 + co;
#pragma unroll
    for (int p = 0; p < 4; ++p) {
      int xv = tx0 + xq * 4 + p;
      if (xv < WWW) Fb[xv * 16] = acc[p];
    }
  }
}

// codes in permuted order: code[bh][t'] = argmax over [rv, -rv] at row ri[t']
__global__ __launch_bounds__(256) void k_codes(
    const float* __restrict__ F, const float* __restrict__ rotT,
    const int* __restrict__ ri, unsigned char* __restrict__ codes) {
  int bh = blockIdx.y;
  int b = bh >> 2, h = bh & 3;
  __shared__ float srot[1024];
  int tid = threadIdx.x;
  for (int i = tid; i < 1024; i += 256) srot[i] = rotT[h * 1024 + i];
  __syncthreads();
  int t = blockIdx.x * 256 + tid;
  if (t >= TL) return;
  int pos = ri[t];
  const float* Fr = F + (b * TL + pos) * 16;
  float q[16];
#pragma unroll
  for (int c = 0; c < 16; ++c) q[c] = Fr[c];
  float best = -1e30f; int bi = 0;
  float worst = 1e30f; int wi = 0;
  for (int j = 0; j < 64; ++j) {
    float v = 0.f;
    const float* rp = srot + j * 16;
#pragma unroll
    for (int c = 0; c < 16; ++c) v = fmaf(q[c], rp[c], v);
    if (v > best)  { best = v;  bi = j; }
    if (v < worst) { worst = v; wi = j; }
  }
  int code = (best >= -worst) ? bi : (64 + wi);
  codes[bh * TL + t] = (unsigned char)code;
}

// stable counting sort per (b,h); emit rank_of[t'] and even-parity chunk counts n0
__global__ __launch_bounds__(256) void k_sort(
    const unsigned char* __restrict__ codes,
    int* __restrict__ rank_of, int* __restrict__ n0g) {
  int bh = blockIdx.x;
  const unsigned char* keys = codes + bh * TL;
  __shared__ unsigned short cnt[240][128];
  __shared__ unsigned int totals[128];
  __shared__ unsigned int baseoff[128];
  __shared__ unsigned int n0s[NCHK];
  int tid = threadIdx.x;
  for (int i = tid; i < 240 * 128 / 2; i += 256) ((unsigned int*)cnt)[i] = 0u;
  for (int i = tid; i < NCHK; i += 256) n0s[i] = 0u;
  __syncthreads();
  const int SEG = 84;
  int base = tid * SEG;
  int nloc = (tid < 240) ? (TL - base) : 0;
  if (nloc > SEG) nloc = SEG;
  if (nloc < 0) nloc = 0;
  for (int e = 0; e < nloc; ++e) cnt[tid][keys[base + e]]++;
  __syncthreads();
  if (tid < 128) {
    unsigned int s = 0;
    for (int g = 0; g < 240; ++g) s += cnt[g][tid];
    totals[tid] = s;
  }
  __syncthreads();
  if (tid == 0) {
    unsigned int run = 0;
    for (int c = 0; c < 128; ++c) { baseoff[c] = run; run += totals[c]; }
  }
  __syncthreads();
  if (tid < 128) {
    unsigned int run = baseoff[tid];
    for (int g = 0; g < 240; ++g) {
      unsigned int v = cnt[g][tid];
      cnt[g][tid] = (unsigned short)run;
      run += v;
    }
  }
  __syncthreads();
  for (int e = 0; e < nloc; ++e) {
    int idx = base + e;
    int c = keys[idx];
    int r = cnt[tid][c]++;
    rank_of[bh * TL + idx] = r;
    if (!(idx & 1)) {
      atomicAdd(&n0s[r / CHK], 1u);
      if (r >= TL - NPAD) atomicAdd(&n0s[NCHK - 1], 1u);
    }
  }
  __syncthreads();
  for (int i = tid; i < NCHK; i += 256) n0g[bh * NCHK + i] = (int)n0s[i];
}

// blocks 0..3: rA/rB point-resblock, LDS-staged; block 4: per-batch E scalars.
__global__ __launch_bounds__(576) void k_point(
    const float* __restrict__ fd1, const float* __restrict__ refin,
    const int* __restrict__ ri, const float* __restrict__ auxT,
    const float* __restrict__ a1b1, const float* __restrict__ a1b2,
    const float* __restrict__ a2b1, const float* __restrict__ a2b2,
    const float* __restrict__ F, float* __restrict__ SC) {
  int tid = threadIdx.x;
  if (blockIdx.x == 4) {
#pragma clang fp contract(off)
    int b = tid;
    if (b >= BN) return;
    int j0 = ri[0], jL = ri[LL];
    const float* qA = F + (b * TL + j0) * 16;
    const float* qB = F + (b * TL + jL) * 16;
    float nA = 0.f, nB = 0.f;
    for (int c = 0; c < 16; ++c) { nA += qA[c] * qA[c]; nB += qB[c] * qB[c]; }
    float mA = fmaxf(sqrtf(nA), 5e-5f), mB = fmaxf(sqrtf(nB), 5e-5f);
    float d00 = 0.f, d01 = 0.f, d10 = 0.f, d11 = 0.f;
    for (int c = 0; c < 16; ++c) {
      float kAc = qA[c] / mA, kBc = qB[c] / mB;
      d00 += qA[c] * kAc; d01 += qA[c] * kBc;
      d10 += qB[c] * kAc; d11 += qB[c] * kBc;
    }
    float zA = (j0 < LL) ? 0.01f : 0.99f;
    float zB = (jL < LL) ? 0.01f : 0.99f;
    float* sc = SC + b * 136;
    sc[0] = expf(d00) * zA; sc[1] = expf(d01) * zB;
    sc[2] = expf(d10) * zA; sc[3] = expf(d11) * zB;
    return;
  }
  int b = blockIdx.x & 1, which = blockIdx.x >> 1;
  int pos = ri[which * LL];
  const float *in, *w1T, *b1, *w2T, *b2;
  int sp;
  if (pos < LL) {
    in = fd1 + b * C0 * LL; w1T = auxT; b1 = a1b1; w2T = auxT + AUXW; b2 = a1b2; sp = pos;
  } else {
    in = refin + b * C0 * LL; w1T = auxT + 2 * AUXW; b1 = a2b1; w2T = auxT + 3 * AUXW;
    b2 = a2b2; sp = pos - LL;
  }
  int y = sp / WWW, x = sp % WWW;

  __shared__ float sPatch[64][25];
  __shared__ float sW[144 * 64];
  __shared__ float sH[9][64];
  __shared__ float sPart[9][64];

  for (int idx = tid; idx < 64 * 25; idx += 576) {
    int ci = idx / 25, pp = idx % 25;
    int gy = y - 2 + pp / 5, gx = x - 2 + pp % 5;
    float v = 0.f;
    if (gy >= 0 && gy < HH && gx >= 0 && gx < WWW) v = in[ci * LL + gy * WWW + gx];
    sPatch[ci][pp] = v;
  }

  int p = tid / 64, ch = tid & 63;
  int p3 = p / 3, pm = p % 3;
  int yy = y + p3 - 1, xx = x + pm - 1;
  bool inb = (yy >= 0) && (yy < HH) && (xx >= 0) && (xx < WWW);

  float acc0 = 0.f, acc1 = 0.f;
  for (int cc = 0; cc < 4; ++cc) {
    __syncthreads();
    for (int i = tid; i < 144 * 64; i += 576) sW[i] = w1T[cc * 9216 + i];
    __syncthreads();
    if (inb) {
#pragma unroll
      for (int ci = 0; ci < 16; ++ci) {
        const float* wp = &sW[ci * 9 * 64 + ch];
        const float* pr = &sPatch[cc * 16 + ci][0];
#pragma unroll
        for (int t = 0; t < 9; ++t) {
          float v = pr[(p3 + t / 3) * 5 + (pm + t % 3)];
          if (ci & 1) acc1 = fmaf(v, wp[t * 64], acc1);
          else        acc0 = fmaf(v, wp[t * 64], acc0);
        }
      }
    }
  }
  sH[p][ch] = inb ? fmaxf(acc0 + acc1 + b1[ch], 0.f) : 0.f;
  __syncthreads();

  {
    float part = 0.f;
    const float* wbase = w2T + p * 64 + ch;
    for (int ci = 0; ci < 64; ++ci) part = fmaf(sH[p][ci], wbase[ci * 9 * 64], part);
    sPart[p][ch] = part;
  }
  __syncthreads();
  if (tid < 64) {
    int co = tid;
    float a = in[co * LL + y * WWW + x] + b2[co];
#pragma unroll
    for (int g = 0; g < 9; ++g) a += sPart[g][co];
    SC[b * 136 + 4 + which * 64 + co] = a;
  }
}

// out[b][c][p]: t = inv[p]; alpha/beta computed inline from rank_of/n0 (fused k_ab).
__global__ __launch_bounds__(256) void k_out(
    const int* __restrict__ inv, const int* __restrict__ rank_of,
    const int* __restrict__ n0, const float* __restrict__ SC,
    float* __restrict__ out) {
  int b = blockIdx.y;
  int p = blockIdx.x * 256 + threadIdx.x;
  if (p >= LL) return;
  int t = inv[p];
  int si = t & 1;
  float e0 = SC[b * 136 + si * 2 + 0];
  float e1 = SC[b * 136 + si * 2 + 1];
  float s0 = 0.f, s1 = 0.f;
  for (int h = 0; h < 4; ++h) {
    int r = rank_of[(b * 4 + h) * TL + t];
    int k = r / CHK;
    int km = (k == 0) ? NCHK - 1 : k - 1;
    int kp = (k == NCHK - 1) ? 0 : k + 1;
    const int* nb = n0 + (b * 4 + h) * NCHK;
    int W0 = nb[k] + nb[km] + nb[kp];
    s0 += (float)W0 * e0;
    s1 += (float)(WINR - W0) * e1;
  }
  float invd = 1.f / (s0 + s1);
  float al = s0 * invd;
  float be = s1 * invd;
  const float* rA = SC + b * 136 + 4;
  const float* rB = rA + 64;
  float* o = out + b * C0 * LL + p;
#pragma unroll
  for (int c = 0; c < 64; ++c) o[c * LL] = al * rA[c] + be * rB[c];
}

}  // namespace

extern "C" void kernel_launch(void* const* d_in, const int* in_sizes, int n_in,
                              void* d_out, int out_size, void* d_ws, size_t ws_size,
                              hipStream_t stream) {
  const float* fd1  = (const float*)d_in[0];
  const float* fd2  = (const float*)d_in[1];
  const float* reff = (const float*)d_in[2];
  const int*   ri   = (const int*)d_in[3];
  const float* mw1  = (const float*)d_in[4];
  const float* mb1  = (const float*)d_in[5];
  const float* mw2  = (const float*)d_in[6];
  const float* mb2  = (const float*)d_in[7];
  const float* mws  = (const float*)d_in[8];
  const float* mbs  = (const float*)d_in[9];
  const float* a1w1 = (const float*)d_in[10];
  const float* a1b1 = (const float*)d_in[11];
  const float* a1w2 = (const float*)d_in[12];
  const float* a1b2 = (const float*)d_in[13];
  const float* a2w1 = (const float*)d_in[14];
  const float* a2b1 = (const float*)d_in[15];
  const float* a2w2 = (const float*)d_in[16];
  const float* a2b2 = (const float*)d_in[17];

  float* ws = (float*)d_ws;
  float* rotT = ws + OFF_ROT;
  float* wT1  = ws + OFF_WT1;
  float* wT2  = ws + OFF_WT2;
  float* wTs  = ws + OFF_WTS;
  float* ht0  = ws + OFF_HT0;
  float* ht1  = ws + OFF_HT1;
  float* ht2  = ws + OFF_HT2;
  float* ht3  = ws + OFF_HT3;
  float* F    = ws + OFF_F;
  float* SC   = ws + OFF_SC;
  unsigned char* codes = (unsigned char*)(ws + OFF_CODE);
  int* rank_of = (int*)(ws + OFF_RANK);
  int* n0      = (int*)(ws + OFF_N0);
  int* invp    = (int*)(ws + OFF_INV);
  float* auxT  = ws + OFF_AUX;

  k_prep<<<dim3(707), dim3(256), 0, stream>>>(mw1, mw2, mws, a1w1, a1w2, a2w1, a2w2,
                                              ri, rotT, wT1, wT2, wTs, auxT, invp);
  k_conv1<<<dim3(784), dim3(256), 0, stream>>>(fd1, fd2, wT1, ht0, ht1, ht2, ht3);
  k_conv2<<<dim3(364), dim3(512), 0, stream>>>(fd1, fd2, ht0, ht1, ht2, ht3, wT2,
                                               mb1, mb2, wTs, mbs, F);
  k_codes<<<dim3(79, 8), dim3(256), 0, stream>>>(F, rotT, ri, codes);
  k_sort<<<dim3(8), dim3(256), 0, stream>>>(codes, rank_of, n0);
  k_point<<<dim3(5), dim3(576), 0, stream>>>(fd1, reff, ri, auxT, a1b1, a1b2,
                                             a2b1, a2b2, F, SC);
  k_out<<<dim3(40, 2), dim3(256), 0, stream>>>(invp, rank_of, n0, SC, (float*)d_out);
}

// Round 8
// 126.690 us; speedup vs baseline: 4.1940x; 1.0480x over previous
//
#include <hip/hip_runtime.h>

// Flip to 0 if absmax fails large: selects legacy (non-partitionable) JAX threefry stream.
#define JAX_THREEFRY_PARTITIONABLE 1

namespace {

constexpr int BN   = 2;      // batch
constexpr int C0   = 64;
constexpr int HH   = 100;
constexpr int WWW  = 100;
constexpr int LL   = 10000;  // H*W
constexpr int TL   = 20000;  // 2L
constexpr int CHK  = 144;
constexpr int NCHK = 139;    // (TL+16)/144
constexpr int NPAD = 16;
constexpr int WINR = 432;    // 3*144

// ws layout in float slots
constexpr int OFF_ROT  = 0;                    // rotT [4][64][16]
constexpr int OFF_WT1  = OFF_ROT + 4096;       // [64*9][16]
constexpr int OFF_WT2  = OFF_WT1 + 9216;       // [16*9][16]
constexpr int OFF_WTS  = OFF_WT2 + 2304;       // [64][16]
constexpr int OFF_HT0  = OFF_WTS + 1024;       // conv1 partial kq=0 [4][16][10000]
constexpr int OFF_HT1  = OFF_HT0 + 640000;     // kq=1
constexpr int OFF_HT2  = OFF_HT1 + 640000;     // kq=2
constexpr int OFF_HT3  = OFF_HT2 + 640000;     // kq=3
constexpr int OFF_F    = OFF_HT3 + 640000;     // F [2][20000][16]
constexpr int OFF_SC   = OFF_F + 640000;       // SC [2][136]
constexpr int OFF_CODE = OFF_SC + 272;         // codes u8 [8][20000]
constexpr int OFF_RANK = OFF_CODE + 40000;     // rank int [8][20000]
constexpr int OFF_N0   = OFF_RANK + 160000;    // n0 int [8][139]
constexpr int OFF_INV  = OFF_N0 + 1112;        // inv int [10000]
constexpr int OFF_AUX  = OFF_INV + 10000;      // auxT: 4 x [576][64]

constexpr int AUXW = 36864;  // 64*64*9

__device__ __forceinline__ unsigned rotl32(unsigned v, int r) {
  return (v << r) | (v >> (32 - r));
}

// JAX threefry2x32, 20 rounds, key injection every 4.
__device__ void tf2x32(unsigned k0, unsigned k1, unsigned x0, unsigned x1,
                       unsigned& o0, unsigned& o1) {
  unsigned ks2 = k0 ^ k1 ^ 0x1BD11BDAu;
  x0 += k0; x1 += k1;
#define TFR(r) { x0 += x1; x1 = rotl32(x1, r); x1 ^= x0; }
  TFR(13) TFR(15) TFR(26) TFR(6)  x0 += k1;  x1 += ks2 + 1u;
  TFR(17) TFR(29) TFR(16) TFR(24) x0 += ks2; x1 += k0 + 2u;
  TFR(13) TFR(15) TFR(26) TFR(6)  x0 += k0;  x1 += k1 + 3u;
  TFR(17) TFR(29) TFR(16) TFR(24) x0 += k1;  x1 += ks2 + 4u;
  TFR(13) TFR(15) TFR(26) TFR(6)  x0 += ks2; x1 += k0 + 5u;
#undef TFR
  o0 = x0; o1 = x1;
}

// XLA's ErfInv32 polynomial (math.cc), no fp contraction to match XLA rounding.
__device__ float xla_erfinv(float x) {
#pragma clang fp contract(off)
  float w = -log1pf(-x * x);
  float p;
  if (w < 5.0f) {
    w = w - 2.5f;
    p = 2.81022636e-08f;
    p = 3.43273939e-07f  + p * w;
    p = -3.5233877e-06f  + p * w;
    p = -4.39150654e-06f + p * w;
    p = 0.00021858087f   + p * w;
    p = -0.00125372503f  + p * w;
    p = -0.00417768164f  + p * w;
    p = 0.246640727f     + p * w;
    p = 1.50140941f      + p * w;
  } else {
    w = sqrtf(w) - 3.0f;
    p = -0.000200214257f;
    p = 0.000100950558f + p * w;
    p = 0.00134934322f  + p * w;
    p = -0.00367342844f + p * w;
    p = 0.00573950773f  + p * w;
    p = -0.0076224613f  + p * w;
    p = 0.00943887047f  + p * w;
    p = 1.00167406f     + p * w;
    p = 2.83297682f     + p * w;
  }
  return p * x;
}

// Merged prep: aux weight transposes + rot RNG + m-weight transposes + inv perm.
__global__ void k_prep(const float* __restrict__ mw1, const float* __restrict__ mw2,
                       const float* __restrict__ mws,
                       const float* __restrict__ a1w1, const float* __restrict__ a1w2,
                       const float* __restrict__ a2w1, const float* __restrict__ a2w2,
                       const int* __restrict__ ri,
                       float* __restrict__ rotT, float* __restrict__ wT1,
                       float* __restrict__ wT2, float* __restrict__ wTs,
                       float* __restrict__ auxT, int* __restrict__ inv) {
  int gid = blockIdx.x * 256 + threadIdx.x;
  if (gid < 4 * AUXW) {
    int wsel = gid / AUXW, j = gid % AUXW;
    const float* src = (wsel == 0) ? a1w1 : (wsel == 1) ? a1w2 : (wsel == 2) ? a2w1 : a2w2;
    int co = j / 576, r = j % 576;                 // coalesced read
    auxT[wsel * AUXW + r * 64 + co] = src[j];
    return;
  }
  int g2 = gid - 4 * AUXW;
  if (g2 < 4096) {
    int i = g2;
    unsigned o0, o1, bits;
#if JAX_THREEFRY_PARTITIONABLE
    tf2x32(0u, 42u, 0u, (unsigned)i, o0, o1);
    bits = o0 ^ o1;
#else
    if (i < 2048) { tf2x32(0u, 42u, (unsigned)i, (unsigned)(i + 2048), o0, o1); bits = o0; }
    else          { tf2x32(0u, 42u, (unsigned)(i - 2048), (unsigned)i, o0, o1); bits = o1; }
#endif
    unsigned fb = (bits >> 9) | 0x3f800000u;
    float f = __uint_as_float(fb) - 1.0f;
    const float lo = __uint_as_float(0xBF7FFFFFu);  // nextafter(-1,0)
    float u = fmaxf(lo, f * 2.0f + lo);
    float r = __uint_as_float(0x3FB504F3u) * xla_erfinv(u);  // sqrt(2)*erfinv(u)
    int c = i >> 8, h = (i >> 6) & 3, j = i & 63;
    rotT[(h * 64 + j) * 16 + c] = r;
    return;
  }
  int g3 = g2 - 4096;
  if (g3 < 9216) {
    { int o = g3 / 576; int r = g3 % 576; wT1[r * 16 + o] = mw1[g3]; }
    if (g3 < 2304) { int o = g3 / 144; int r = g3 % 144; wT2[r * 16 + o] = mw2[g3]; }
    if (g3 < 1024) { int o = g3 / 64;  int ci = g3 % 64; wTs[ci * 16 + o] = mws[g3]; }
    return;
  }
  int g4 = g3 - 9216;
  if (g4 < TL) {
    int p = ri[g4];
    if (p < LL) inv[p] = g4;
  }
}

// conv1 (m-block, 64->16 3x3), K-split in 4 quarters of 16 ci.
// block = (img n, kq, 8y x 16x tile); 512 threads = (co, xq, yl); 4 px per thread.
// Same (cc, c4, dy, dx) summation nesting as before -> bit-identical partials.
__global__ __launch_bounds__(512) void k_conv1(
    const float* __restrict__ fd1, const float* __restrict__ fd2,
    const float* __restrict__ wT1,
    float* __restrict__ ht0, float* __restrict__ ht1,
    float* __restrict__ ht2, float* __restrict__ ht3) {
  // grid = 1456 = 8*182 exactly; XCD swizzle keeps kq-siblings + neighbor tiles
  // on one XCD's L2.
  int x = blockIdx.x;
  int blk = (x & 7) * 182 + (x >> 3);
  int kq = blk & 3;
  int rest = blk >> 2;                   // 0..363 = img n (0..3) x 91 tiles
  int n = rest / 91, tile = rest % 91;
  int yt = tile / 7, xt = tile % 7;      // 13 y-tiles x 7 x-tiles
  int ty0 = yt * 8, tx0 = xt * 16;
  const float* in = ((n >> 1) ? fd2 : fd1) + (n & 1) * (C0 * LL) + (kq * 16) * LL;
  float* htk = ((kq == 0) ? ht0 : (kq == 1) ? ht1 : (kq == 2) ? ht2 : ht3) + n * 16 * LL;
  int tid = threadIdx.x;
  int co = tid & 15, xq = (tid >> 4) & 3, yl = tid >> 6;   // yl 0..7

  __shared__ float sIn[16 * 10 * 20];   // [ci][10 rows][20 pad (18 used)] (12.8KB)
  __shared__ float sW[144 * 16];        // this quarter's weights [(ci*9+t)][co] (9.2KB)

  for (int i = tid; i < 144 * 16; i += 512) sW[i] = wT1[kq * 2304 + i];
  for (int idx = tid; idx < 16 * 10 * 18; idx += 512) {
    int ci = idx / 180, r = idx % 180, iy = r / 18, ix = r % 18;
    int gy = ty0 - 1 + iy, gx = tx0 - 1 + ix;
    float v = 0.f;
    if (gy >= 0 && gy < HH && gx >= 0 && gx < WWW) v = in[ci * LL + gy * WWW + gx];
    sIn[ci * 200 + iy * 20 + ix] = v;
  }
  __syncthreads();

  float acc[4];
#pragma unroll
  for (int p = 0; p < 4; ++p) acc[p] = 0.f;

  for (int cc = 0; cc < 4; ++cc) {   // 4-ci chunks
    float w[4][9];
#pragma unroll
    for (int c4 = 0; c4 < 4; ++c4)
#pragma unroll
      for (int t = 0; t < 9; ++t)
        w[c4][t] = sW[((cc * 4 + c4) * 9 + t) * 16 + co];
#pragma unroll
    for (int c4 = 0; c4 < 4; ++c4) {
      const float* rowb = &sIn[(cc * 4 + c4) * 200 + yl * 20 + xq * 4];
#pragma unroll
      for (int dy = 0; dy < 3; ++dy) {
        const float* r = rowb + dy * 20;
        float v[6];
#pragma unroll
        for (int k = 0; k < 6; ++k) v[k] = r[k];
#pragma unroll
        for (int dx = 0; dx < 3; ++dx) {
          float wv = w[c4][dy * 3 + dx];
#pragma unroll
          for (int p = 0; p < 4; ++p) acc[p] = fmaf(v[p + dx], wv, acc[p]);
        }
      }
    }
  }

  int yv = ty0 + yl;
  int xg = tx0 + xq * 4;
  if (yv < HH && xg < WWW) {   // xg multiple of 4; 100 % 4 == 0, no straddle
    float4 s = make_float4(acc[0], acc[1], acc[2], acc[3]);
    *(float4*)&htk[co * LL + yv * WWW + xg] = s;
  }
}

// conv2 (16->16 3x3 + b2) + skip (1x1 64->16 + mbs), with h = relu(sum ht + mb1)
// fused into the halo staging.
// block = (img n, 8y x 16x tile); 512 threads = (co, xq, yl); 4 px per thread.
__global__ __launch_bounds__(512) void k_conv2(
    const float* __restrict__ fd1, const float* __restrict__ fd2,
    const float* __restrict__ ht0, const float* __restrict__ ht1,
    const float* __restrict__ ht2, const float* __restrict__ ht3,
    const float* __restrict__ wT2, const float* __restrict__ mb1,
    const float* __restrict__ mb2, const float* __restrict__ wTs,
    const float* __restrict__ mbs, float* __restrict__ F) {
  // XCD swizzle for 364 blocks: bijective 46/45 chunking (364 = 4*46 + 4*45).
  int xx = blockIdx.x;
  int xcd = xx & 7, slot = xx >> 3;
  int blk = (xcd < 4) ? (xcd * 46 + slot) : (184 + (xcd - 4) * 45 + slot);
  int n = blk / 91, tile = blk % 91;
  int yt = tile / 7, xt = tile % 7;       // 13 y-tiles x 7 x-tiles
  int ty0 = yt * 8, tx0 = xt * 16;
  int src = n >> 1, b = n & 1;
  const float* in = (src ? fd2 : fd1) + b * (C0 * LL);
  const float* h0 = ht0 + n * 16 * LL;
  const float* h1 = ht1 + n * 16 * LL;
  const float* h2 = ht2 + n * 16 * LL;
  const float* h3 = ht3 + n * 16 * LL;
  int tid = threadIdx.x;
  int co = tid & 15, xq = (tid >> 4) & 3, yl = tid >> 6;   // yl 0..7

  __shared__ float sW2[144 * 16];         // [(ci*9+t)][co]
  __shared__ float sWs[64 * 16];          // [ci][co]
  __shared__ float sH[16 * 10 * 20];      // h halo [ci][10 rows][20 pad (18 used)]
  __shared__ float sSkip[16 * 8 * 17];    // skip chunk [ci16][8][17 pad (16 used)]

  for (int i = tid; i < 144 * 16; i += 512) sW2[i] = wT2[i];
  for (int i = tid; i < 64 * 16; i += 512) sWs[i] = wTs[i];
  for (int idx = tid; idx < 16 * 10 * 18; idx += 512) {
    int ci = idx / 180, r = idx % 180, iy = r / 18, ix = r % 18;
    int gy = ty0 - 1 + iy, gx = tx0 - 1 + ix;
    float v = 0.f;
    if (gy >= 0 && gy < HH && gx >= 0 && gx < WWW) {
      int o = ci * LL + gy * WWW + gx;
      v = fmaxf(h0[o] + h1[o] + h2[o] + h3[o] + mb1[ci], 0.f);
    }
    sH[ci * 200 + iy * 20 + ix] = v;
  }
  __syncthreads();

  float acc[4];
  float bias = mb2[co] + mbs[co];
#pragma unroll
  for (int p = 0; p < 4; ++p) acc[p] = bias;

  // conv 3x3 over the 16 h-channels
  for (int ci = 0; ci < 16; ++ci) {
    const float* rowb = &sH[ci * 200 + yl * 20 + xq * 4];
#pragma unroll
    for (int dy = 0; dy < 3; ++dy) {
      const float* r = rowb + dy * 20;
      float v[6];
#pragma unroll
      for (int k = 0; k < 6; ++k) v[k] = r[k];
#pragma unroll
      for (int dx = 0; dx < 3; ++dx) {
        float wv = sW2[(ci * 9 + dy * 3 + dx) * 16 + co];
#pragma unroll
        for (int p = 0; p < 4; ++p) acc[p] = fmaf(v[p + dx], wv, acc[p]);
      }
    }
  }

  // skip 1x1 over 64 ci, staged in 4 chunks of 16 ci
  for (int cc = 0; cc < 4; ++cc) {
    __syncthreads();
    for (int idx = tid; idx < 16 * 8 * 16; idx += 512) {
      int ci = idx >> 7, r = idx & 127, iy = r >> 4, ix = r & 15;
      int gy = ty0 + iy, gx = tx0 + ix;
      float v = 0.f;
      if (gy < HH && gx < WWW) v = in[(cc * 16 + ci) * LL + gy * WWW + gx];
      sSkip[(ci * 8 + iy) * 17 + ix] = v;
    }
    __syncthreads();
    for (int c16 = 0; c16 < 16; ++c16) {
      float wv = sWs[(cc * 16 + c16) * 16 + co];
      const float* sv = &sSkip[(c16 * 8 + yl) * 17 + xq * 4];
#pragma unroll
      for (int p = 0; p < 4; ++p) acc[p] = fmaf(sv[p], wv, acc[p]);
    }
  }

  int yv = ty0 + yl;
  if (yv < HH) {
    float* Fb = F + (b * TL + src * LL + yv * WWW) * 16 + co;
#pragma unroll
    for (int p = 0; p < 4; ++p) {
      int xv = tx0 + xq * 4 + p;
      if (xv < WWW) Fb[xv * 16] = acc[p];
    }
  }
}

// Flat 285-block kernel, 576 threads:
//  blocks 0..279   : codes (35 segs x 8 bh)
//  blocks 280..283 : rA/rB point-resblock
//  block  284      : per-batch E scalars
__global__ __launch_bounds__(576) void k_codes(
    const float* __restrict__ F, const float* __restrict__ rotT,
    const int* __restrict__ ri, unsigned char* __restrict__ codes,
    const float* __restrict__ fd1, const float* __restrict__ refin,
    const float* __restrict__ auxT,
    const float* __restrict__ a1b1, const float* __restrict__ a1b2,
    const float* __restrict__ a2b1, const float* __restrict__ a2b2,
    float* __restrict__ SC) {
  int blk = blockIdx.x;
  int tid = threadIdx.x;

  if (blk < 280) {
    int bh = blk / 35, seg = blk % 35;
    int b = bh >> 2, h = bh & 3;
    __shared__ float srot[1024];
    for (int i = tid; i < 1024; i += 576) srot[i] = rotT[h * 1024 + i];
    __syncthreads();
    int t = seg * 576 + tid;
    if (t >= TL) return;
    int pos = ri[t];
    const float* Fr = F + (b * TL + pos) * 16;
    float q[16];
#pragma unroll
    for (int c = 0; c < 16; ++c) q[c] = Fr[c];
    float best = -1e30f; int bi = 0;
    float worst = 1e30f; int wi = 0;
    for (int j = 0; j < 64; ++j) {
      float v = 0.f;
      const float* rp = srot + j * 16;
#pragma unroll
      for (int c = 0; c < 16; ++c) v = fmaf(q[c], rp[c], v);
      if (v > best)  { best = v;  bi = j; }
      if (v < worst) { worst = v; wi = j; }
    }
    int code = (best >= -worst) ? bi : (64 + wi);
    codes[bh * TL + t] = (unsigned char)code;
    return;
  }

  if (blk == 284) {
#pragma clang fp contract(off)
    int b = tid;
    if (b >= BN) return;
    int j0 = ri[0], jL = ri[LL];
    const float* qA = F + (b * TL + j0) * 16;
    const float* qB = F + (b * TL + jL) * 16;
    float nA = 0.f, nB = 0.f;
    for (int c = 0; c < 16; ++c) { nA += qA[c] * qA[c]; nB += qB[c] * qB[c]; }
    float mA = fmaxf(sqrtf(nA), 5e-5f), mB = fmaxf(sqrtf(nB), 5e-5f);
    float d00 = 0.f, d01 = 0.f, d10 = 0.f, d11 = 0.f;
    for (int c = 0; c < 16; ++c) {
      float kAc = qA[c] / mA, kBc = qB[c] / mB;
      d00 += qA[c] * kAc; d01 += qA[c] * kBc;
      d10 += qB[c] * kAc; d11 += qB[c] * kBc;
    }
    float zA = (j0 < LL) ? 0.01f : 0.99f;
    float zB = (jL < LL) ? 0.01f : 0.99f;
    float* sc = SC + b * 136;
    sc[0] = expf(d00) * zA; sc[1] = expf(d01) * zB;
    sc[2] = expf(d10) * zA; sc[3] = expf(d11) * zB;
    return;
  }

  // point-resblock path (blocks 280..283)
  int pb = blk - 280;
  int b = pb & 1, which = pb >> 1;
  int pos = ri[which * LL];
  const float *in, *w1T, *b1, *w2T, *b2;
  int sp;
  if (pos < LL) {
    in = fd1 + b * C0 * LL; w1T = auxT; b1 = a1b1; w2T = auxT + AUXW; b2 = a1b2; sp = pos;
  } else {
    in = refin + b * C0 * LL; w1T = auxT + 2 * AUXW; b1 = a2b1; w2T = auxT + 3 * AUXW;
    b2 = a2b2; sp = pos - LL;
  }
  int y = sp / WWW, x = sp % WWW;

  __shared__ float sPatch[64][25];
  __shared__ float sW[144 * 64];
  __shared__ float sH[9][64];
  __shared__ float sPart[9][64];

  for (int idx = tid; idx < 64 * 25; idx += 576) {
    int ci = idx / 25, pp = idx % 25;
    int gy = y - 2 + pp / 5, gx = x - 2 + pp % 5;
    float v = 0.f;
    if (gy >= 0 && gy < HH && gx >= 0 && gx < WWW) v = in[ci * LL + gy * WWW + gx];
    sPatch[ci][pp] = v;
  }

  int p = tid / 64, ch = tid & 63;
  int p3 = p / 3, pm = p % 3;
  int yy = y + p3 - 1, xx = x + pm - 1;
  bool inb = (yy >= 0) && (yy < HH) && (xx >= 0) && (xx < WWW);

  float acc0 = 0.f, acc1 = 0.f;
  for (int cc = 0; cc < 4; ++cc) {
    __syncthreads();
    for (int i = tid; i < 144 * 64; i += 576) sW[i] = w1T[cc * 9216 + i];
    __syncthreads();
    if (inb) {
#pragma unroll
      for (int ci = 0; ci < 16; ++ci) {
        const float* wp = &sW[ci * 9 * 64 + ch];
        const float* pr = &sPatch[cc * 16 + ci][0];
#pragma unroll
        for (int t = 0; t < 9; ++t) {
          float v = pr[(p3 + t / 3) * 5 + (pm + t % 3)];
          if (ci & 1) acc1 = fmaf(v, wp[t * 64], acc1);
          else        acc0 = fmaf(v, wp[t * 64], acc0);
        }
      }
    }
  }
  sH[p][ch] = inb ? fmaxf(acc0 + acc1 + b1[ch], 0.f) : 0.f;
  __syncthreads();

  {
    float part = 0.f;
    const float* wbase = w2T + p * 64 + ch;
    for (int ci = 0; ci < 64; ++ci) part = fmaf(sH[p][ci], wbase[ci * 9 * 64], part);
    sPart[p][ch] = part;
  }
  __syncthreads();
  if (tid < 64) {
    int co = tid;
    float a = in[co * LL + y * WWW + x] + b2[co];
#pragma unroll
    for (int g = 0; g < 9; ++g) a += sPart[g][co];
    SC[b * 136 + 4 + which * 64 + co] = a;
  }
}

// stable counting sort per (b,h); emit rank_of[t'] and even-parity chunk counts n0
__global__ __launch_bounds__(256) void k_sort(
    const unsigned char* __restrict__ codes,
    int* __restrict__ rank_of, int* __restrict__ n0g) {
  int bh = blockIdx.x;
  const unsigned char* keys = codes + bh * TL;
  __shared__ unsigned short cnt[240][128];
  __shared__ unsigned int totals[128];
  __shared__ unsigned int baseoff[128];
  __shared__ unsigned int n0s[NCHK];
  int tid = threadIdx.x;
  for (int i = tid; i < 240 * 128 / 2; i += 256) ((unsigned int*)cnt)[i] = 0u;
  for (int i = tid; i < NCHK; i += 256) n0s[i] = 0u;
  __syncthreads();
  const int SEG = 84;
  int base = tid * SEG;
  int nloc = (tid < 240) ? (TL - base) : 0;
  if (nloc > SEG) nloc = SEG;
  if (nloc < 0) nloc = 0;
  for (int e = 0; e < nloc; ++e) cnt[tid][keys[base + e]]++;
  __syncthreads();
  if (tid < 128) {
    unsigned int s = 0;
    for (int g = 0; g < 240; ++g) s += cnt[g][tid];
    totals[tid] = s;
  }
  __syncthreads();
  if (tid == 0) {
    unsigned int run = 0;
    for (int c = 0; c < 128; ++c) { baseoff[c] = run; run += totals[c]; }
  }
  __syncthreads();
  if (tid < 128) {
    unsigned int run = baseoff[tid];
    for (int g = 0; g < 240; ++g) {
      unsigned int v = cnt[g][tid];
      cnt[g][tid] = (unsigned short)run;
      run += v;
    }
  }
  __syncthreads();
  for (int e = 0; e < nloc; ++e) {
    int idx = base + e;
    int c = keys[idx];
    int r = cnt[tid][c]++;
    rank_of[bh * TL + idx] = r;
    if (!(idx & 1)) {
      atomicAdd(&n0s[r / CHK], 1u);
      if (r >= TL - NPAD) atomicAdd(&n0s[NCHK - 1], 1u);
    }
  }
  __syncthreads();
  for (int i = tid; i < NCHK; i += 256) n0g[bh * NCHK + i] = (int)n0s[i];
}

// out[b][c][p]: t = inv[p]; alpha/beta computed inline from rank_of/n0 (fused k_ab).
// c-split 4 ways (blockIdx.z) for occupancy on this gather-latency-bound kernel.
__global__ __launch_bounds__(256) void k_out(
    const int* __restrict__ inv, const int* __restrict__ rank_of,
    const int* __restrict__ n0, const float* __restrict__ SC,
    float* __restrict__ out) {
  int b = blockIdx.y;
  int c0 = blockIdx.z * 16;
  int p = blockIdx.x * 256 + threadIdx.x;
  if (p >= LL) return;
  int t = inv[p];
  int si = t & 1;
  float e0 = SC[b * 136 + si * 2 + 0];
  float e1 = SC[b * 136 + si * 2 + 1];
  float s0 = 0.f, s1 = 0.f;
  for (int h = 0; h < 4; ++h) {
    int r = rank_of[(b * 4 + h) * TL + t];
    int k = r / CHK;
    int km = (k == 0) ? NCHK - 1 : k - 1;
    int kp = (k == NCHK - 1) ? 0 : k + 1;
    const int* nb = n0 + (b * 4 + h) * NCHK;
    int W0 = nb[k] + nb[km] + nb[kp];
    s0 += (float)W0 * e0;
    s1 += (float)(WINR - W0) * e1;
  }
  float invd = 1.f / (s0 + s1);
  float al = s0 * invd;
  float be = s1 * invd;
  const float* rA = SC + b * 136 + 4;
  const float* rB = rA + 64;
  float* o = out + b * C0 * LL + p;
#pragma unroll
  for (int c = 0; c < 16; ++c) o[(c0 + c) * LL] = al * rA[c0 + c] + be * rB[c0 + c];
}

}  // namespace

extern "C" void kernel_launch(void* const* d_in, const int* in_sizes, int n_in,
                              void* d_out, int out_size, void* d_ws, size_t ws_size,
                              hipStream_t stream) {
  const float* fd1  = (const float*)d_in[0];
  const float* fd2  = (const float*)d_in[1];
  const float* reff = (const float*)d_in[2];
  const int*   ri   = (const int*)d_in[3];
  const float* mw1  = (const float*)d_in[4];
  const float* mb1  = (const float*)d_in[5];
  const float* mw2  = (const float*)d_in[6];
  const float* mb2  = (const float*)d_in[7];
  const float* mws  = (const float*)d_in[8];
  const float* mbs  = (const float*)d_in[9];
  const float* a1w1 = (const float*)d_in[10];
  const float* a1b1 = (const float*)d_in[11];
  const float* a1w2 = (const float*)d_in[12];
  const float* a1b2 = (const float*)d_in[13];
  const float* a2w1 = (const float*)d_in[14];
  const float* a2b1 = (const float*)d_in[15];
  const float* a2w2 = (const float*)d_in[16];
  const float* a2b2 = (const float*)d_in[17];

  float* ws = (float*)d_ws;
  float* rotT = ws + OFF_ROT;
  float* wT1  = ws + OFF_WT1;
  float* wT2  = ws + OFF_WT2;
  float* wTs  = ws + OFF_WTS;
  float* ht0  = ws + OFF_HT0;
  float* ht1  = ws + OFF_HT1;
  float* ht2  = ws + OFF_HT2;
  float* ht3  = ws + OFF_HT3;
  float* F    = ws + OFF_F;
  float* SC   = ws + OFF_SC;
  unsigned char* codes = (unsigned char*)(ws + OFF_CODE);
  int* rank_of = (int*)(ws + OFF_RANK);
  int* n0      = (int*)(ws + OFF_N0);
  int* invp    = (int*)(ws + OFF_INV);
  float* auxT  = ws + OFF_AUX;

  k_prep<<<dim3(707), dim3(256), 0, stream>>>(mw1, mw2, mws, a1w1, a1w2, a2w1, a2w2,
                                              ri, rotT, wT1, wT2, wTs, auxT, invp);
  k_conv1<<<dim3(1456), dim3(512), 0, stream>>>(fd1, fd2, wT1, ht0, ht1, ht2, ht3);
  k_conv2<<<dim3(364), dim3(512), 0, stream>>>(fd1, fd2, ht0, ht1, ht2, ht3, wT2,
                                               mb1, mb2, wTs, mbs, F);
  k_codes<<<dim3(285), dim3(576), 0, stream>>>(F, rotT, ri, codes, fd1, reff, auxT,
                                               a1b1, a1b2, a2b1, a2b2, SC);
  k_sort<<<dim3(8), dim3(256), 0, stream>>>(codes, rank_of, n0);
  k_out<<<dim3(40, 2, 4), dim3(256), 0, stream>>>(invp, rank_of, n0, SC, (float*)d_out);
}